// Round 1
// baseline (2625.383 us; speedup 1.0000x reference)
//
#include <hip/hip_runtime.h>
#include <stdint.h>

#define S_LEN 2048
#define NB 2
#define DIM 1024
#define NHEAD 16
#define DHEAD 64
#define FFN_DIM 4096
#define NEXP 8
#define NTOK 4096  // S*B

typedef __attribute__((ext_vector_type(8))) short short8;
typedef __attribute__((ext_vector_type(4))) short short4v;
typedef __attribute__((ext_vector_type(4))) float f32x4;

__device__ __forceinline__ short f2bf(float f) {
  unsigned u = __float_as_uint(f);
  unsigned r = (u + 0x7FFFu + ((u >> 16) & 1u)) >> 16;
  return (short)(unsigned short)r;
}
__device__ __forceinline__ float bf2f(short s) {
  return __uint_as_float(((unsigned)(unsigned short)s) << 16);
}
__device__ __forceinline__ void async_ld16(const short* g, short* l) {
  __builtin_amdgcn_global_load_lds(
      (const __attribute__((address_space(1))) void*)g,
      (__attribute__((address_space(3))) void*)l, 16, 0, 0);
}

// ---------------- LayerNorm: fp32 in -> bf16 out ----------------
__global__ __launch_bounds__(256) void ln_kernel(const float* __restrict__ x,
                                                 const float* __restrict__ g,
                                                 const float* __restrict__ b,
                                                 short* __restrict__ out) {
  int t = blockIdx.x, tid = threadIdx.x;
  const float* row = x + (size_t)t * DIM;
  float4 v = *(const float4*)(row + tid * 4);
  __shared__ float sb1[4], sb2[4];
  float s = v.x + v.y + v.z + v.w;
  for (int off = 32; off; off >>= 1) s += __shfl_xor(s, off, 64);
  if ((tid & 63) == 0) sb1[tid >> 6] = s;
  __syncthreads();
  float mean = (sb1[0] + sb1[1] + sb1[2] + sb1[3]) * (1.0f / DIM);
  float d0 = v.x - mean, d1 = v.y - mean, d2 = v.z - mean, d3 = v.w - mean;
  float q = d0 * d0 + d1 * d1 + d2 * d2 + d3 * d3;
  for (int off = 32; off; off >>= 1) q += __shfl_xor(q, off, 64);
  if ((tid & 63) == 0) sb2[tid >> 6] = q;
  __syncthreads();
  float var = (sb2[0] + sb2[1] + sb2[2] + sb2[3]) * (1.0f / DIM);
  float rstd = rsqrtf(var + 1e-5f);
  int c = tid * 4;
  float4 gg = *(const float4*)(g + c);
  float4 bb = *(const float4*)(b + c);
  short4v o;
  o.x = f2bf(d0 * rstd * gg.x + bb.x);
  o.y = f2bf(d1 * rstd * gg.y + bb.y);
  o.z = f2bf(d2 * rstd * gg.z + bb.z);
  o.w = f2bf(d3 * rstd * gg.w + bb.w);
  *(short4v*)(out + (size_t)t * DIM + c) = o;
}

// ---------------- GEMM: C[M,N] = A[M,K](bf16) @ B[N,K](f32->bf16)^T ----------
// EPI: 0=+bias->bf16(qkv)  1=+bias+resid->f32  2=silu->bf16  3=*=prev bf16  4=*wrow->f32
template <int EPI, bool EXPERT, bool GATHER>
__global__ __launch_bounds__(256) void gemm_k(
    const short* __restrict__ A, const float* __restrict__ Bw, int N, int K,
    const float* __restrict__ bias, const float* __restrict__ resid,
    short* __restrict__ outb, float* __restrict__ outf,
    const int* __restrict__ counts, const int* __restrict__ offsets,
    const int* __restrict__ tok_list, const float* __restrict__ wlist) {
  int mt = blockIdx.x, nt = blockIdx.y;
  int e = EXPERT ? blockIdx.z : 0;
  int cnt = 0, aoff = 0;
  if (EXPERT) {
    cnt = counts[e];
    if (mt * 128 >= cnt) return;
    aoff = offsets[e];
  }
  const float* Be = Bw + (size_t)e * N * K;
  int m0 = mt * 128, n0 = nt * 128;
  int tid = threadIdx.x;
  int wave = tid >> 6, lane = tid & 63;
  int quad = lane >> 4, lr = lane & 15;
  int wr = wave >> 1, wc = wave & 1;

  __shared__ short As[128 * 32];
  __shared__ short Bs[128 * 32];

  // A staging: 512 chunks of 16B; chunk q=(wave*128+c*64+lane): row=q>>2, kc=q&3
  int q0c = wave * 128 + lane, q1c = wave * 128 + 64 + lane;
  int row0 = q0c >> 2, kc0 = q0c & 3;
  int row1 = q1c >> 2, kc1 = q1c & 3;
  size_t ar0, ar1;
  if (GATHER) {
    int i0 = m0 + row0; if (i0 > cnt - 1) i0 = cnt - 1;
    int i1 = m0 + row1; if (i1 > cnt - 1) i1 = cnt - 1;
    ar0 = (size_t)tok_list[aoff + i0];
    ar1 = (size_t)tok_list[aoff + i1];
  } else if (EXPERT) {
    int i0 = m0 + row0; if (i0 > cnt - 1) i0 = cnt - 1;
    int i1 = m0 + row1; if (i1 > cnt - 1) i1 = cnt - 1;
    ar0 = (size_t)(aoff + i0);
    ar1 = (size_t)(aoff + i1);
  } else {
    ar0 = (size_t)(m0 + row0);
    ar1 = (size_t)(m0 + row1);
  }
  const short* Ap0 = A + ar0 * K + kc0 * 8;
  const short* Ap1 = A + ar1 * K + kc1 * 8;

  int nrow = tid >> 1, half = tid & 1;
  const float* bp = Be + (size_t)(n0 + nrow) * K + half * 16;

  f32x4 acc[4][4];
#pragma unroll
  for (int i = 0; i < 4; i++)
#pragma unroll
    for (int j = 0; j < 4; j++) acc[i][j] = (f32x4){0.f, 0.f, 0.f, 0.f};

  for (int k0 = 0; k0 < K; k0 += 32) {
    async_ld16(Ap0 + k0, As + wave * 1024);
    async_ld16(Ap1 + k0, As + wave * 1024 + 512);
    float4 f0 = *(const float4*)(bp + k0);
    float4 f1 = *(const float4*)(bp + k0 + 4);
    float4 f2 = *(const float4*)(bp + k0 + 8);
    float4 f3 = *(const float4*)(bp + k0 + 12);
    short8 p0, p1;
    p0[0] = f2bf(f0.x); p0[1] = f2bf(f0.y); p0[2] = f2bf(f0.z); p0[3] = f2bf(f0.w);
    p0[4] = f2bf(f1.x); p0[5] = f2bf(f1.y); p0[6] = f2bf(f1.z); p0[7] = f2bf(f1.w);
    p1[0] = f2bf(f2.x); p1[1] = f2bf(f2.y); p1[2] = f2bf(f2.z); p1[3] = f2bf(f2.w);
    p1[4] = f2bf(f3.x); p1[5] = f2bf(f3.y); p1[6] = f2bf(f3.z); p1[7] = f2bf(f3.w);
    *(short8*)&Bs[nrow * 32 + half * 16] = p0;
    *(short8*)&Bs[nrow * 32 + half * 16 + 8] = p1;
    __syncthreads();
    short8 af[4], bf[4];
#pragma unroll
    for (int i = 0; i < 4; i++)
      af[i] = *(const short8*)&As[(wr * 64 + i * 16 + lr) * 32 + quad * 8];
#pragma unroll
    for (int j = 0; j < 4; j++)
      bf[j] = *(const short8*)&Bs[(wc * 64 + j * 16 + lr) * 32 + quad * 8];
#pragma unroll
    for (int i = 0; i < 4; i++)
#pragma unroll
      for (int j = 0; j < 4; j++)
        acc[i][j] = __builtin_amdgcn_mfma_f32_16x16x32_bf16(af[i], bf[j], acc[i][j], 0, 0, 0);
    __syncthreads();
  }

#pragma unroll
  for (int i = 0; i < 4; i++) {
    int rbase = wr * 64 + i * 16 + quad * 4;
#pragma unroll
    for (int j = 0; j < 4; j++) {
      int c = n0 + wc * 64 + j * 16 + lr;
#pragma unroll
      for (int r = 0; r < 4; r++) {
        int rl = rbase + r;
        float v = acc[i][j][r];
        if (EPI == 0) {
          int t = m0 + rl;
          outb[(size_t)t * N + c] = f2bf(v + bias[c]);
        } else if (EPI == 1) {
          int t = m0 + rl;
          size_t idx = (size_t)t * N + c;
          outf[idx] = v + bias[c] + resid[idx];
        } else if (EPI == 2) {
          int rg = m0 + rl;
          if (rg < cnt)
            outb[(size_t)(aoff + rg) * N + c] = f2bf(v / (1.0f + __expf(-v)));
        } else if (EPI == 3) {
          int rg = m0 + rl;
          if (rg < cnt) {
            size_t idx = (size_t)(aoff + rg) * N + c;
            outb[idx] = f2bf(v * bf2f(outb[idx]));
          }
        } else {
          int rg = m0 + rl;
          if (rg < cnt) {
            size_t slot = (size_t)(aoff + rg);
            outf[slot * N + c] = v * wlist[slot];
          }
        }
      }
    }
  }
}

// ---------------- Flash attention: 4 waves x 16 q-rows per block -------------
__global__ __launch_bounds__(256) void attn_kernel(const short* __restrict__ qkv,
                                                   short* __restrict__ oa) {
  int qt = blockIdx.x;  // 0..31 (64 q rows each)
  int bh = blockIdx.y;  // b*16+h
  int b_ = bh >> 4, h = bh & 15;
  int tid = threadIdx.x, wave = tid >> 6, lane = tid & 63;
  int quad = lane >> 4, lr = lane & 15;

  __shared__ short Ks[32 * 72];
  __shared__ short Vt[64 * 40];
  __shared__ short Ps[4 * 16 * 40];

  int sq = qt * 64 + wave * 16 + lr;
  const short* qrow = qkv + (size_t)(sq * NB + b_) * 3072 + h * 64;
  short8 qa0 = *(const short8*)(qrow + quad * 8);
  short8 qa1 = *(const short8*)(qrow + 32 + quad * 8);

  f32x4 oacc[4];
#pragma unroll
  for (int n = 0; n < 4; n++) oacc[n] = (f32x4){0.f, 0.f, 0.f, 0.f};
  float mrow[4], lsum[4];
#pragma unroll
  for (int r = 0; r < 4; r++) { mrow[r] = -1e30f; lsum[r] = 0.f; }

  int krow = tid >> 3, kpart = tid & 7;
  const float scale = 0.125f;  // 1/sqrt(64)

  for (int kt = 0; kt < S_LEN / 32; kt++) {
    __syncthreads();
    int sk = kt * 32 + krow;
    const short* kr = qkv + (size_t)(sk * NB + b_) * 3072 + 1024 + h * 64 + kpart * 8;
    *(short8*)&Ks[krow * 72 + kpart * 8] = *(const short8*)kr;
    const short* vr = qkv + (size_t)(sk * NB + b_) * 3072 + 2048 + h * 64 + kpart * 8;
    short8 vv = *(const short8*)vr;
#pragma unroll
    for (int j = 0; j < 8; j++) Vt[(kpart * 8 + j) * 40 + krow] = vv[j];
    __syncthreads();

    f32x4 sc[2];
#pragma unroll
    for (int g = 0; g < 2; g++) {
      short8 kb0 = *(const short8*)&Ks[(g * 16 + lr) * 72 + quad * 8];
      short8 kb1 = *(const short8*)&Ks[(g * 16 + lr) * 72 + 32 + quad * 8];
      f32x4 z = (f32x4){0.f, 0.f, 0.f, 0.f};
      z = __builtin_amdgcn_mfma_f32_16x16x32_bf16(qa0, kb0, z, 0, 0, 0);
      z = __builtin_amdgcn_mfma_f32_16x16x32_bf16(qa1, kb1, z, 0, 0, 0);
      sc[g] = z;
    }
    float alpha[4];
#pragma unroll
    for (int r = 0; r < 4; r++) {
      float s0 = sc[0][r] * scale, s1 = sc[1][r] * scale;
      float mx = fmaxf(s0, s1);
      mx = fmaxf(mx, __shfl_xor(mx, 1, 64));
      mx = fmaxf(mx, __shfl_xor(mx, 2, 64));
      mx = fmaxf(mx, __shfl_xor(mx, 4, 64));
      mx = fmaxf(mx, __shfl_xor(mx, 8, 64));
      float mnew = fmaxf(mrow[r], mx);
      alpha[r] = __expf(mrow[r] - mnew);
      float p0 = __expf(s0 - mnew), p1 = __expf(s1 - mnew);
      sc[0][r] = p0; sc[1][r] = p1;
      float ps = p0 + p1;
      ps += __shfl_xor(ps, 1, 64);
      ps += __shfl_xor(ps, 2, 64);
      ps += __shfl_xor(ps, 4, 64);
      ps += __shfl_xor(ps, 8, 64);
      lsum[r] = lsum[r] * alpha[r] + ps;
      mrow[r] = mnew;
    }
#pragma unroll
    for (int n = 0; n < 4; n++)
#pragma unroll
      for (int r = 0; r < 4; r++) oacc[n][r] *= alpha[r];
    short* pw = Ps + wave * 16 * 40;
#pragma unroll
    for (int r = 0; r < 4; r++) {
      pw[(quad * 4 + r) * 40 + lr] = f2bf(sc[0][r]);
      pw[(quad * 4 + r) * 40 + 16 + lr] = f2bf(sc[1][r]);
    }
    __syncthreads();
    short8 pf = *(const short8*)&pw[lr * 40 + quad * 8];
#pragma unroll
    for (int n = 0; n < 4; n++) {
      short8 vf = *(const short8*)&Vt[(n * 16 + lr) * 40 + quad * 8];
      oacc[n] = __builtin_amdgcn_mfma_f32_16x16x32_bf16(pf, vf, oacc[n], 0, 0, 0);
    }
  }
#pragma unroll
  for (int r = 0; r < 4; r++) {
    int srow = qt * 64 + wave * 16 + quad * 4 + r;
    short* orow = oa + (size_t)(srow * NB + b_) * 1024 + h * 64;
    float inv = 1.0f / lsum[r];
#pragma unroll
    for (int n = 0; n < 4; n++) orow[n * 16 + lr] = f2bf(oacc[n][r] * inv);
  }
}

// ---------------- Router: full fp32 LN2 + gate logits + top-2 ----------------
__global__ __launch_bounds__(256) void router_kernel(
    const float* __restrict__ xa, const float* __restrict__ g2,
    const float* __restrict__ b2, const float* __restrict__ gate,
    float* __restrict__ logits_out, int* __restrict__ topi,
    float* __restrict__ topw, int* __restrict__ counts) {
  int t = blockIdx.x, tid = threadIdx.x;
  const float* row = xa + (size_t)t * DIM;
  float4 v = *(const float4*)(row + tid * 4);
  __shared__ float sb1[4], sb2[4];
  __shared__ float rede[4][8];
  float s = v.x + v.y + v.z + v.w;
  for (int off = 32; off; off >>= 1) s += __shfl_xor(s, off, 64);
  if ((tid & 63) == 0) sb1[tid >> 6] = s;
  __syncthreads();
  float mean = (sb1[0] + sb1[1] + sb1[2] + sb1[3]) * (1.0f / DIM);
  float d0 = v.x - mean, d1 = v.y - mean, d2 = v.z - mean, d3 = v.w - mean;
  float q = d0 * d0 + d1 * d1 + d2 * d2 + d3 * d3;
  for (int off = 32; off; off >>= 1) q += __shfl_xor(q, off, 64);
  if ((tid & 63) == 0) sb2[tid >> 6] = q;
  __syncthreads();
  float var = (sb2[0] + sb2[1] + sb2[2] + sb2[3]) * (1.0f / DIM);
  float rstd = rsqrtf(var + 1e-5f);
  int c = tid * 4;
  float4 gg = *(const float4*)(g2 + c);
  float4 bb = *(const float4*)(b2 + c);
  float h0 = d0 * rstd * gg.x + bb.x, h1 = d1 * rstd * gg.y + bb.y;
  float h2v = d2 * rstd * gg.z + bb.z, h3 = d3 * rstd * gg.w + bb.w;
  float lg[8];
#pragma unroll
  for (int e = 0; e < 8; e++) {
    float4 gw = *(const float4*)(gate + e * DIM + c);
    lg[e] = h0 * gw.x + h1 * gw.y + h2v * gw.z + h3 * gw.w;
  }
#pragma unroll
  for (int e = 0; e < 8; e++)
    for (int off = 32; off; off >>= 1) lg[e] += __shfl_xor(lg[e], off, 64);
  if ((tid & 63) == 0)
#pragma unroll
    for (int e = 0; e < 8; e++) rede[tid >> 6][e] = lg[e];
  __syncthreads();
  if (tid == 0) {
    float L[8];
#pragma unroll
    for (int e = 0; e < 8; e++)
      L[e] = rede[0][e] + rede[1][e] + rede[2][e] + rede[3][e];
#pragma unroll
    for (int e = 0; e < 8; e++) logits_out[(size_t)t * 8 + e] = L[e];
    int i1 = 0;
    for (int e = 1; e < 8; e++) if (L[e] > L[i1]) i1 = e;
    int i2 = (i1 == 0) ? 1 : 0;
    for (int e = 0; e < 8; e++) if (e != i1 && L[e] > L[i2]) i2 = e;
    float mx = fmaxf(L[i1], L[i2]);
    float p1 = __expf(L[i1] - mx), p2 = __expf(L[i2] - mx);
    float inv = 1.0f / (p1 + p2);
    topi[t * 2] = i1; topi[t * 2 + 1] = i2;
    topw[t * 2] = p1 * inv; topw[t * 2 + 1] = p2 * inv;
    atomicAdd(&counts[i1], 1);
    atomicAdd(&counts[i2], 1);
  }
}

__global__ void scan_kernel(const int* __restrict__ counts, int* __restrict__ offsets,
                            int* __restrict__ cursors) {
  if (threadIdx.x == 0) {
    int acc = 0;
    for (int e = 0; e < 8; e++) {
      offsets[e] = acc;
      cursors[e] = acc;
      acc += counts[e];
    }
  }
}

__global__ __launch_bounds__(256) void scatter_kernel(
    const int* __restrict__ topi, const float* __restrict__ topw,
    int* __restrict__ cursors, int* __restrict__ tok_list,
    float* __restrict__ wlist, int* __restrict__ slot_of) {
  int t = blockIdx.x * 256 + threadIdx.x;
  if (t >= NTOK) return;
#pragma unroll
  for (int k = 0; k < 2; k++) {
    int e = topi[t * 2 + k];
    int pos = atomicAdd(&cursors[e], 1);
    tok_list[pos] = t;
    wlist[pos] = topw[t * 2 + k];
    slot_of[t * 2 + k] = pos;
  }
}

__global__ __launch_bounds__(256) void final_kernel(
    const float* __restrict__ xa, const float* __restrict__ h2,
    const int* __restrict__ slot_of, float* __restrict__ out) {
  size_t i = ((size_t)blockIdx.x * 256 + threadIdx.x) * 4;
  int t = (int)(i >> 10);
  int c = (int)(i & 1023);
  float4 a = *(const float4*)(xa + i);
  int s0 = slot_of[t * 2], s1 = slot_of[t * 2 + 1];
  float4 m0 = *(const float4*)(h2 + (size_t)s0 * 1024 + c);
  float4 m1 = *(const float4*)(h2 + (size_t)s1 * 1024 + c);
  float4 o;
  o.x = a.x + m0.x + m1.x;
  o.y = a.y + m0.y + m1.y;
  o.z = a.z + m0.z + m1.z;
  o.w = a.w + m0.w + m1.w;
  *(float4*)(out + i) = o;
}

extern "C" void kernel_launch(void* const* d_in, const int* in_sizes, int n_in,
                              void* d_out, int out_size, void* d_ws, size_t ws_size,
                              hipStream_t stream) {
  const float* x = (const float*)d_in[0];
  const float* in_w = (const float*)d_in[1];
  const float* in_b = (const float*)d_in[2];
  const float* out_w = (const float*)d_in[3];
  const float* out_b = (const float*)d_in[4];
  const float* ln1g = (const float*)d_in[5];
  const float* ln1b = (const float*)d_in[6];
  const float* ln2g = (const float*)d_in[7];
  const float* ln2b = (const float*)d_in[8];
  const float* gate = (const float*)d_in[9];
  const float* w1 = (const float*)d_in[10];
  const float* w2 = (const float*)d_in[11];
  const float* w3 = (const float*)d_in[12];
  float* out0 = (float*)d_out;
  float* logits = out0 + (size_t)NTOK * DIM;

  char* ws = (char*)d_ws;
  const size_t MB = 1u << 20;
  short* x_ln1 = (short*)(ws);             // 8 MB   [dead after QKV]
  short* qkv = (short*)(ws + 8 * MB);      // 24 MB  [dead after attn]
  short* o_attn = (short*)(ws + 32 * MB);  // 8 MB   [dead after outproj]
  float* x_att = (float*)(ws + 40 * MB);   // 16 MB  [live to end]
  short* x_ln2 = (short*)(ws + 56 * MB);   // 8 MB
  short* s1 = (short*)(ws + 64 * MB);      // 64 MB
  float* h2 = (float*)(ws);                // 32 MB  (reuses x_ln1+qkv region)
  char* ctrl = ws + 128 * MB;
  int* counts = (int*)ctrl;
  int* offsets = counts + 8;
  int* cursors = counts + 16;
  int* topi = (int*)(ctrl + 256);
  float* topw = (float*)(ctrl + 256 + 32 * 1024);
  int* slot_of = (int*)(ctrl + 256 + 64 * 1024);
  int* tok_list = (int*)(ctrl + 256 + 96 * 1024);
  float* wlist = (float*)(ctrl + 256 + 128 * 1024);

  hipMemsetAsync(counts, 0, 32, stream);
  ln_kernel<<<NTOK, 256, 0, stream>>>(x, ln1g, ln1b, x_ln1);
  gemm_k<0, false, false><<<dim3(32, 24, 1), 256, 0, stream>>>(
      x_ln1, in_w, 3072, 1024, in_b, nullptr, qkv, nullptr, nullptr, nullptr, nullptr, nullptr);
  attn_kernel<<<dim3(32, 32), 256, 0, stream>>>(qkv, o_attn);
  gemm_k<1, false, false><<<dim3(32, 8, 1), 256, 0, stream>>>(
      o_attn, out_w, 1024, 1024, out_b, x, nullptr, x_att, nullptr, nullptr, nullptr, nullptr);
  ln_kernel<<<NTOK, 256, 0, stream>>>(x_att, ln2g, ln2b, x_ln2);
  router_kernel<<<NTOK, 256, 0, stream>>>(x_att, ln2g, ln2b, gate, logits, topi, topw, counts);
  scan_kernel<<<1, 64, 0, stream>>>(counts, offsets, cursors);
  scatter_kernel<<<16, 256, 0, stream>>>(topi, topw, cursors, tok_list, wlist, slot_of);
  gemm_k<2, true, true><<<dim3(32, 32, 8), 256, 0, stream>>>(
      x_ln2, w1, 4096, 1024, nullptr, nullptr, s1, nullptr, counts, offsets, tok_list, wlist);
  gemm_k<3, true, true><<<dim3(32, 32, 8), 256, 0, stream>>>(
      x_ln2, w3, 4096, 1024, nullptr, nullptr, s1, nullptr, counts, offsets, tok_list, wlist);
  gemm_k<4, true, false><<<dim3(32, 8, 8), 256, 0, stream>>>(
      s1, w2, 1024, 4096, nullptr, nullptr, nullptr, h2, counts, offsets, tok_list, wlist);
  final_kernel<<<4096, 256, 0, stream>>>(x_att, h2, slot_of, out0);
}

// Round 2
// 1376.937 us; speedup vs baseline: 1.9067x; 1.9067x over previous
//
#include <hip/hip_runtime.h>
#include <stdint.h>

#define S_LEN 2048
#define NB 2
#define DIM 1024
#define NHEAD 16
#define DHEAD 64
#define FFN_DIM 4096
#define NEXP 8
#define NTOK 4096  // S*B

typedef __attribute__((ext_vector_type(8))) short short8;
typedef __attribute__((ext_vector_type(4))) short short4v;
typedef __attribute__((ext_vector_type(4))) float f32x4;

__device__ __forceinline__ short f2bf(float f) {
  unsigned u = __float_as_uint(f);
  unsigned r = (u + 0x7FFFu + ((u >> 16) & 1u)) >> 16;
  return (short)(unsigned short)r;
}
__device__ __forceinline__ void async_ld16(const short* g, short* l) {
  __builtin_amdgcn_global_load_lds(
      (const __attribute__((address_space(1))) void*)g,
      (__attribute__((address_space(3))) void*)l, 16, 0, 0);
}

// ---------------- fp32 -> bf16 weight conversion (coalesced) ----------------
__global__ __launch_bounds__(256) void cvt_kernel(const float* __restrict__ src,
                                                  short* __restrict__ dst, int n) {
  int i = (blockIdx.x * 256 + threadIdx.x) * 8;
  if (i >= n) return;
  float4 a = *(const float4*)(src + i);
  float4 b = *(const float4*)(src + i + 4);
  short8 o;
  o[0] = f2bf(a.x); o[1] = f2bf(a.y); o[2] = f2bf(a.z); o[3] = f2bf(a.w);
  o[4] = f2bf(b.x); o[5] = f2bf(b.y); o[6] = f2bf(b.z); o[7] = f2bf(b.w);
  *(short8*)(dst + i) = o;
}

// ---------------- LayerNorm: fp32 in -> bf16 out ----------------
__global__ __launch_bounds__(256) void ln_kernel(const float* __restrict__ x,
                                                 const float* __restrict__ g,
                                                 const float* __restrict__ b,
                                                 short* __restrict__ out) {
  int t = blockIdx.x, tid = threadIdx.x;
  const float* row = x + (size_t)t * DIM;
  float4 v = *(const float4*)(row + tid * 4);
  __shared__ float sb1[4], sb2[4];
  float s = v.x + v.y + v.z + v.w;
  for (int off = 32; off; off >>= 1) s += __shfl_xor(s, off, 64);
  if ((tid & 63) == 0) sb1[tid >> 6] = s;
  __syncthreads();
  float mean = (sb1[0] + sb1[1] + sb1[2] + sb1[3]) * (1.0f / DIM);
  float d0 = v.x - mean, d1 = v.y - mean, d2 = v.z - mean, d3 = v.w - mean;
  float q = d0 * d0 + d1 * d1 + d2 * d2 + d3 * d3;
  for (int off = 32; off; off >>= 1) q += __shfl_xor(q, off, 64);
  if ((tid & 63) == 0) sb2[tid >> 6] = q;
  __syncthreads();
  float var = (sb2[0] + sb2[1] + sb2[2] + sb2[3]) * (1.0f / DIM);
  float rstd = rsqrtf(var + 1e-5f);
  int c = tid * 4;
  float4 gg = *(const float4*)(g + c);
  float4 bb = *(const float4*)(b + c);
  short4v o;
  o.x = f2bf(d0 * rstd * gg.x + bb.x);
  o.y = f2bf(d1 * rstd * gg.y + bb.y);
  o.z = f2bf(d2 * rstd * gg.z + bb.z);
  o.w = f2bf(d3 * rstd * gg.w + bb.w);
  *(short4v*)(out + (size_t)t * DIM + c) = o;
}

// ---------------- GEMM: C[M,N] = A[M,K](bf16) @ B[N,K](bf16)^T ---------------
// All staging via global_load_lds width=16 (m97 structure).
// EPI: 0=+bias->bf16(qkv)  1=+bias+resid->f32  4=*wrow->f32  5=silu(a1)*a3->bf16
// Grid: (nt, mt, e) so all mt sharing a B tile land on the same XCD (nt%8).
template <int EPI, bool EXPERT, bool GATHER, bool DUAL>
__global__ __launch_bounds__(256) void gemm_k(
    const short* __restrict__ A, const short* __restrict__ B1w,
    const short* __restrict__ B2w, int N, int K,
    const float* __restrict__ bias, const float* __restrict__ resid,
    short* __restrict__ outb, float* __restrict__ outf,
    const int* __restrict__ counts, const int* __restrict__ offsets,
    const int* __restrict__ tok_list, const float* __restrict__ wlist) {
  int nt = blockIdx.x, mt = blockIdx.y;
  int e = EXPERT ? blockIdx.z : 0;
  int cnt = 0, aoff = 0;
  if (EXPERT) {
    cnt = counts[e];
    if (mt * 128 >= cnt) return;
    aoff = offsets[e];
  }
  const short* Be1 = B1w + (size_t)e * N * K;
  const short* Be3 = DUAL ? (B2w + (size_t)e * N * K) : nullptr;
  int m0 = mt * 128, n0 = nt * 128;
  int tid = threadIdx.x;
  int wave = tid >> 6, lane = tid & 63;
  int quad = lane >> 4, lr = lane & 15;
  int wr = wave >> 1, wc = wave & 1;

  extern __shared__ short smem[];
  short* As = smem;           // 128x32
  short* Bs1 = smem + 4096;   // 128x32
  short* Bs3 = smem + 8192;   // 128x32 (DUAL only)

  // staging chunks: 512 x 16B per tile; chunk q: row=q>>2, kcol=q&3
  int q0c = wave * 128 + lane, q1c = q0c + 64;
  int row0 = q0c >> 2, kc0 = q0c & 3;
  int row1 = q1c >> 2, kc1 = q1c & 3;
  size_t ar0, ar1;
  if (GATHER) {
    int i0 = m0 + row0; if (i0 > cnt - 1) i0 = cnt - 1;
    int i1 = m0 + row1; if (i1 > cnt - 1) i1 = cnt - 1;
    ar0 = (size_t)tok_list[aoff + i0];
    ar1 = (size_t)tok_list[aoff + i1];
  } else if (EXPERT) {
    int i0 = m0 + row0; if (i0 > cnt - 1) i0 = cnt - 1;
    int i1 = m0 + row1; if (i1 > cnt - 1) i1 = cnt - 1;
    ar0 = (size_t)(aoff + i0);
    ar1 = (size_t)(aoff + i1);
  } else {
    ar0 = (size_t)(m0 + row0);
    ar1 = (size_t)(m0 + row1);
  }
  const short* Ap0 = A + ar0 * K + kc0 * 8;
  const short* Ap1 = A + ar1 * K + kc1 * 8;
  const short* Bp0 = Be1 + (size_t)(n0 + row0) * K + kc0 * 8;
  const short* Bp1 = Be1 + (size_t)(n0 + row1) * K + kc1 * 8;
  const short* Cp0 = DUAL ? (Be3 + (size_t)(n0 + row0) * K + kc0 * 8) : nullptr;
  const short* Cp1 = DUAL ? (Be3 + (size_t)(n0 + row1) * K + kc1 * 8) : nullptr;

  f32x4 acc[4][4];
  f32x4 acc3[DUAL ? 4 : 1][DUAL ? 4 : 1];
#pragma unroll
  for (int i = 0; i < 4; i++)
#pragma unroll
    for (int j = 0; j < 4; j++) acc[i][j] = (f32x4){0.f, 0.f, 0.f, 0.f};
  if (DUAL) {
#pragma unroll
    for (int i = 0; i < 4; i++)
#pragma unroll
      for (int j = 0; j < 4; j++) acc3[i][j] = (f32x4){0.f, 0.f, 0.f, 0.f};
  }

  for (int k0 = 0; k0 < K; k0 += 32) {
    async_ld16(Ap0 + k0, As + wave * 1024);
    async_ld16(Ap1 + k0, As + wave * 1024 + 512);
    async_ld16(Bp0 + k0, Bs1 + wave * 1024);
    async_ld16(Bp1 + k0, Bs1 + wave * 1024 + 512);
    if (DUAL) {
      async_ld16(Cp0 + k0, Bs3 + wave * 1024);
      async_ld16(Cp1 + k0, Bs3 + wave * 1024 + 512);
    }
    __syncthreads();
    short8 af[4], bf[4];
#pragma unroll
    for (int i = 0; i < 4; i++)
      af[i] = *(const short8*)&As[(wr * 64 + i * 16 + lr) * 32 + quad * 8];
#pragma unroll
    for (int j = 0; j < 4; j++)
      bf[j] = *(const short8*)&Bs1[(wc * 64 + j * 16 + lr) * 32 + quad * 8];
#pragma unroll
    for (int i = 0; i < 4; i++)
#pragma unroll
      for (int j = 0; j < 4; j++)
        acc[i][j] = __builtin_amdgcn_mfma_f32_16x16x32_bf16(af[i], bf[j], acc[i][j], 0, 0, 0);
    if (DUAL) {
      short8 cf[4];
#pragma unroll
      for (int j = 0; j < 4; j++)
        cf[j] = *(const short8*)&Bs3[(wc * 64 + j * 16 + lr) * 32 + quad * 8];
#pragma unroll
      for (int i = 0; i < 4; i++)
#pragma unroll
        for (int j = 0; j < 4; j++)
          acc3[i][j] = __builtin_amdgcn_mfma_f32_16x16x32_bf16(af[i], cf[j], acc3[i][j], 0, 0, 0);
    }
    __syncthreads();
  }

#pragma unroll
  for (int i = 0; i < 4; i++) {
    int rbase = wr * 64 + i * 16 + quad * 4;
#pragma unroll
    for (int j = 0; j < 4; j++) {
      int c = n0 + wc * 64 + j * 16 + lr;
#pragma unroll
      for (int r = 0; r < 4; r++) {
        int rl = rbase + r;
        float v = acc[i][j][r];
        if (EPI == 0) {
          int t = m0 + rl;
          outb[(size_t)t * N + c] = f2bf(v + bias[c]);
        } else if (EPI == 1) {
          int t = m0 + rl;
          size_t idx = (size_t)t * N + c;
          outf[idx] = v + bias[c] + resid[idx];
        } else if (EPI == 4) {
          int rg = m0 + rl;
          if (rg < cnt) {
            size_t slot = (size_t)(aoff + rg);
            outf[slot * N + c] = v * wlist[slot];
          }
        } else {  // 5: silu(acc)*acc3 -> bf16
          int rg = m0 + rl;
          if (rg < cnt) {
            float v3 = acc3[i][j][r];
            float sv = v / (1.0f + __expf(-v));
            outb[(size_t)(aoff + rg) * N + c] = f2bf(sv * v3);
          }
        }
      }
    }
  }
}

// ---------------- Flash attention: 4 waves x 16 q-rows per block -------------
__global__ __launch_bounds__(256) void attn_kernel(const short* __restrict__ qkv,
                                                   short* __restrict__ oa) {
  int qt = blockIdx.x;  // 0..31 (64 q rows each)
  int bh = blockIdx.y;  // b*16+h
  int b_ = bh >> 4, h = bh & 15;
  int tid = threadIdx.x, wave = tid >> 6, lane = tid & 63;
  int quad = lane >> 4, lr = lane & 15;

  __shared__ short Ks[32 * 72];
  __shared__ short Vt[64 * 40];
  __shared__ short Ps[4 * 16 * 40];

  int sq = qt * 64 + wave * 16 + lr;
  const short* qrow = qkv + (size_t)(sq * NB + b_) * 3072 + h * 64;
  short8 qa0 = *(const short8*)(qrow + quad * 8);
  short8 qa1 = *(const short8*)(qrow + 32 + quad * 8);

  f32x4 oacc[4];
#pragma unroll
  for (int n = 0; n < 4; n++) oacc[n] = (f32x4){0.f, 0.f, 0.f, 0.f};
  float mrow[4], lsum[4];
#pragma unroll
  for (int r = 0; r < 4; r++) { mrow[r] = -1e30f; lsum[r] = 0.f; }

  int krow = tid >> 3, kpart = tid & 7;
  const float scale = 0.125f;  // 1/sqrt(64)

  for (int kt = 0; kt < S_LEN / 32; kt++) {
    __syncthreads();
    int sk = kt * 32 + krow;
    const short* kr = qkv + (size_t)(sk * NB + b_) * 3072 + 1024 + h * 64 + kpart * 8;
    *(short8*)&Ks[krow * 72 + kpart * 8] = *(const short8*)kr;
    const short* vr = qkv + (size_t)(sk * NB + b_) * 3072 + 2048 + h * 64 + kpart * 8;
    short8 vv = *(const short8*)vr;
#pragma unroll
    for (int j = 0; j < 8; j++) Vt[(kpart * 8 + j) * 40 + krow] = vv[j];
    __syncthreads();

    f32x4 sc[2];
#pragma unroll
    for (int g = 0; g < 2; g++) {
      short8 kb0 = *(const short8*)&Ks[(g * 16 + lr) * 72 + quad * 8];
      short8 kb1 = *(const short8*)&Ks[(g * 16 + lr) * 72 + 32 + quad * 8];
      f32x4 z = (f32x4){0.f, 0.f, 0.f, 0.f};
      z = __builtin_amdgcn_mfma_f32_16x16x32_bf16(qa0, kb0, z, 0, 0, 0);
      z = __builtin_amdgcn_mfma_f32_16x16x32_bf16(qa1, kb1, z, 0, 0, 0);
      sc[g] = z;
    }
    float alpha[4];
#pragma unroll
    for (int r = 0; r < 4; r++) {
      float s0 = sc[0][r] * scale, s1 = sc[1][r] * scale;
      float mx = fmaxf(s0, s1);
      mx = fmaxf(mx, __shfl_xor(mx, 1, 64));
      mx = fmaxf(mx, __shfl_xor(mx, 2, 64));
      mx = fmaxf(mx, __shfl_xor(mx, 4, 64));
      mx = fmaxf(mx, __shfl_xor(mx, 8, 64));
      float mnew = fmaxf(mrow[r], mx);
      alpha[r] = __expf(mrow[r] - mnew);
      float p0 = __expf(s0 - mnew), p1 = __expf(s1 - mnew);
      sc[0][r] = p0; sc[1][r] = p1;
      float ps = p0 + p1;
      ps += __shfl_xor(ps, 1, 64);
      ps += __shfl_xor(ps, 2, 64);
      ps += __shfl_xor(ps, 4, 64);
      ps += __shfl_xor(ps, 8, 64);
      lsum[r] = lsum[r] * alpha[r] + ps;
      mrow[r] = mnew;
    }
#pragma unroll
    for (int n = 0; n < 4; n++)
#pragma unroll
      for (int r = 0; r < 4; r++) oacc[n][r] *= alpha[r];
    short* pw = Ps + wave * 16 * 40;
#pragma unroll
    for (int r = 0; r < 4; r++) {
      pw[(quad * 4 + r) * 40 + lr] = f2bf(sc[0][r]);
      pw[(quad * 4 + r) * 40 + 16 + lr] = f2bf(sc[1][r]);
    }
    __syncthreads();
    short8 pf = *(const short8*)&pw[lr * 40 + quad * 8];
#pragma unroll
    for (int n = 0; n < 4; n++) {
      short8 vf = *(const short8*)&Vt[(n * 16 + lr) * 40 + quad * 8];
      oacc[n] = __builtin_amdgcn_mfma_f32_16x16x32_bf16(pf, vf, oacc[n], 0, 0, 0);
    }
  }
#pragma unroll
  for (int r = 0; r < 4; r++) {
    int srow = qt * 64 + wave * 16 + quad * 4 + r;
    short* orow = oa + (size_t)(srow * NB + b_) * 1024 + h * 64;
    float inv = 1.0f / lsum[r];
#pragma unroll
    for (int n = 0; n < 4; n++) orow[n * 16 + lr] = f2bf(oacc[n][r] * inv);
  }
}

// ---------------- Router: full fp32 LN2 + gate logits + top-2 ----------------
__global__ __launch_bounds__(256) void router_kernel(
    const float* __restrict__ xa, const float* __restrict__ g2,
    const float* __restrict__ b2, const float* __restrict__ gate,
    float* __restrict__ logits_out, int* __restrict__ topi,
    float* __restrict__ topw, int* __restrict__ counts) {
  int t = blockIdx.x, tid = threadIdx.x;
  const float* row = xa + (size_t)t * DIM;
  float4 v = *(const float4*)(row + tid * 4);
  __shared__ float sb1[4], sb2[4];
  __shared__ float rede[4][8];
  float s = v.x + v.y + v.z + v.w;
  for (int off = 32; off; off >>= 1) s += __shfl_xor(s, off, 64);
  if ((tid & 63) == 0) sb1[tid >> 6] = s;
  __syncthreads();
  float mean = (sb1[0] + sb1[1] + sb1[2] + sb1[3]) * (1.0f / DIM);
  float d0 = v.x - mean, d1 = v.y - mean, d2 = v.z - mean, d3 = v.w - mean;
  float q = d0 * d0 + d1 * d1 + d2 * d2 + d3 * d3;
  for (int off = 32; off; off >>= 1) q += __shfl_xor(q, off, 64);
  if ((tid & 63) == 0) sb2[tid >> 6] = q;
  __syncthreads();
  float var = (sb2[0] + sb2[1] + sb2[2] + sb2[3]) * (1.0f / DIM);
  float rstd = rsqrtf(var + 1e-5f);
  int c = tid * 4;
  float4 gg = *(const float4*)(g2 + c);
  float4 bb = *(const float4*)(b2 + c);
  float h0 = d0 * rstd * gg.x + bb.x, h1 = d1 * rstd * gg.y + bb.y;
  float h2v = d2 * rstd * gg.z + bb.z, h3 = d3 * rstd * gg.w + bb.w;
  float lg[8];
#pragma unroll
  for (int e = 0; e < 8; e++) {
    float4 gw = *(const float4*)(gate + e * DIM + c);
    lg[e] = h0 * gw.x + h1 * gw.y + h2v * gw.z + h3 * gw.w;
  }
#pragma unroll
  for (int e = 0; e < 8; e++)
    for (int off = 32; off; off >>= 1) lg[e] += __shfl_xor(lg[e], off, 64);
  if ((tid & 63) == 0)
#pragma unroll
    for (int e = 0; e < 8; e++) rede[tid >> 6][e] = lg[e];
  __syncthreads();
  if (tid == 0) {
    float L[8];
#pragma unroll
    for (int e = 0; e < 8; e++)
      L[e] = rede[0][e] + rede[1][e] + rede[2][e] + rede[3][e];
#pragma unroll
    for (int e = 0; e < 8; e++) logits_out[(size_t)t * 8 + e] = L[e];
    int i1 = 0;
    for (int e = 1; e < 8; e++) if (L[e] > L[i1]) i1 = e;
    int i2 = (i1 == 0) ? 1 : 0;
    for (int e = 0; e < 8; e++) if (e != i1 && L[e] > L[i2]) i2 = e;
    float mx = fmaxf(L[i1], L[i2]);
    float p1 = __expf(L[i1] - mx), p2 = __expf(L[i2] - mx);
    float inv = 1.0f / (p1 + p2);
    topi[t * 2] = i1; topi[t * 2 + 1] = i2;
    topw[t * 2] = p1 * inv; topw[t * 2 + 1] = p2 * inv;
    atomicAdd(&counts[i1], 1);
    atomicAdd(&counts[i2], 1);
  }
}

__global__ void scan_kernel(const int* __restrict__ counts, int* __restrict__ offsets,
                            int* __restrict__ cursors) {
  if (threadIdx.x == 0) {
    int acc = 0;
    for (int e = 0; e < 8; e++) {
      offsets[e] = acc;
      cursors[e] = acc;
      acc += counts[e];
    }
  }
}

__global__ __launch_bounds__(256) void scatter_kernel(
    const int* __restrict__ topi, const float* __restrict__ topw,
    int* __restrict__ cursors, int* __restrict__ tok_list,
    float* __restrict__ wlist, int* __restrict__ slot_of) {
  int t = blockIdx.x * 256 + threadIdx.x;
  if (t >= NTOK) return;
#pragma unroll
  for (int k = 0; k < 2; k++) {
    int e = topi[t * 2 + k];
    int pos = atomicAdd(&cursors[e], 1);
    tok_list[pos] = t;
    wlist[pos] = topw[t * 2 + k];
    slot_of[t * 2 + k] = pos;
  }
}

__global__ __launch_bounds__(256) void final_kernel(
    const float* __restrict__ xa, const float* __restrict__ h2,
    const int* __restrict__ slot_of, float* __restrict__ out) {
  size_t i = ((size_t)blockIdx.x * 256 + threadIdx.x) * 4;
  int t = (int)(i >> 10);
  int c = (int)(i & 1023);
  float4 a = *(const float4*)(xa + i);
  int s0 = slot_of[t * 2], s1 = slot_of[t * 2 + 1];
  float4 m0 = *(const float4*)(h2 + (size_t)s0 * 1024 + c);
  float4 m1 = *(const float4*)(h2 + (size_t)s1 * 1024 + c);
  float4 o;
  o.x = a.x + m0.x + m1.x;
  o.y = a.y + m0.y + m1.y;
  o.z = a.z + m0.z + m1.z;
  o.w = a.w + m0.w + m1.w;
  *(float4*)(out + i) = o;
}

extern "C" void kernel_launch(void* const* d_in, const int* in_sizes, int n_in,
                              void* d_out, int out_size, void* d_ws, size_t ws_size,
                              hipStream_t stream) {
  const float* x = (const float*)d_in[0];
  const float* in_w = (const float*)d_in[1];
  const float* in_b = (const float*)d_in[2];
  const float* out_w = (const float*)d_in[3];
  const float* out_b = (const float*)d_in[4];
  const float* ln1g = (const float*)d_in[5];
  const float* ln1b = (const float*)d_in[6];
  const float* ln2g = (const float*)d_in[7];
  const float* ln2b = (const float*)d_in[8];
  const float* gate = (const float*)d_in[9];
  const float* w1 = (const float*)d_in[10];
  const float* w2 = (const float*)d_in[11];
  const float* w3 = (const float*)d_in[12];
  float* out0 = (float*)d_out;
  float* logits = out0 + (size_t)NTOK * DIM;

  char* ws = (char*)d_ws;
  const size_t MB = 1u << 20;
  // Liveness-overlaid layout (~289 MB):
  short* w1b = (short*)(ws);                // [0,64)   dead after w1w3
  short* w3b = (short*)(ws + 64 * MB);      // [64,128) dead after w1w3
  short* w2b = (short*)(ws + 128 * MB);     // [128,192)
  short* in_wb = (short*)(ws + 192 * MB);   // [192,198)
  short* out_wb = (short*)(ws + 198 * MB);  // [198,200)
  short* x_ln1 = (short*)(ws + 200 * MB);   // dead after qkv   } inside s1
  short* qkv = (short*)(ws + 208 * MB);     // dead after attn  } region
  short* o_attn = (short*)(ws + 232 * MB);  // dead after outprj} (written later)
  short* s1 = (short*)(ws + 200 * MB);      // [200,264) written by w1w3
  float* h2 = (float*)(ws);                 // [0,32) overlays w1b (dead)
  float* x_att = (float*)(ws + 264 * MB);   // [264,280) live to end
  short* x_ln2 = (short*)(ws + 280 * MB);   // [280,288)
  char* ctrl = ws + 288 * MB;
  int* counts = (int*)ctrl;
  int* offsets = counts + 8;
  int* cursors = counts + 16;
  int* topi = (int*)(ctrl + 256);
  float* topw = (float*)(ctrl + 256 + 32 * 1024);
  int* slot_of = (int*)(ctrl + 256 + 64 * 1024);
  int* tok_list = (int*)(ctrl + 256 + 96 * 1024);
  float* wlist = (float*)(ctrl + 256 + 128 * 1024);

  hipMemsetAsync(counts, 0, 32, stream);
  // weight conversions (once per launch)
  cvt_kernel<<<(NEXP * FFN_DIM * DIM) / 8 / 256, 256, 0, stream>>>(w1, w1b, NEXP * FFN_DIM * DIM);
  cvt_kernel<<<(NEXP * FFN_DIM * DIM) / 8 / 256, 256, 0, stream>>>(w3, w3b, NEXP * FFN_DIM * DIM);
  cvt_kernel<<<(NEXP * FFN_DIM * DIM) / 8 / 256, 256, 0, stream>>>(w2, w2b, NEXP * DIM * FFN_DIM);
  cvt_kernel<<<(3 * DIM * DIM) / 8 / 256, 256, 0, stream>>>(in_w, in_wb, 3 * DIM * DIM);
  cvt_kernel<<<(DIM * DIM) / 8 / 256, 256, 0, stream>>>(out_w, out_wb, DIM * DIM);

  ln_kernel<<<NTOK, 256, 0, stream>>>(x, ln1g, ln1b, x_ln1);
  gemm_k<0, false, false, false><<<dim3(24, 32, 1), 256, 16384, stream>>>(
      x_ln1, in_wb, nullptr, 3072, 1024, in_b, nullptr, qkv, nullptr,
      nullptr, nullptr, nullptr, nullptr);
  attn_kernel<<<dim3(32, 32), 256, 0, stream>>>(qkv, o_attn);
  gemm_k<1, false, false, false><<<dim3(8, 32, 1), 256, 16384, stream>>>(
      o_attn, out_wb, nullptr, 1024, 1024, out_b, x, nullptr, x_att,
      nullptr, nullptr, nullptr, nullptr);
  ln_kernel<<<NTOK, 256, 0, stream>>>(x_att, ln2g, ln2b, x_ln2);
  router_kernel<<<NTOK, 256, 0, stream>>>(x_att, ln2g, ln2b, gate, logits, topi, topw, counts);
  scan_kernel<<<1, 64, 0, stream>>>(counts, offsets, cursors);
  scatter_kernel<<<16, 256, 0, stream>>>(topi, topw, cursors, tok_list, wlist, slot_of);
  // fused w1/w3 -> s1 = silu(x@w1^T) * (x@w3^T)
  gemm_k<5, true, true, true><<<dim3(32, 32, 8), 256, 24576, stream>>>(
      x_ln2, w1b, w3b, FFN_DIM, DIM, nullptr, nullptr, s1, nullptr,
      counts, offsets, tok_list, wlist);
  // w2: h2 = (s1 @ w2^T) * combine_weight
  gemm_k<4, true, false, false><<<dim3(8, 32, 8), 256, 16384, stream>>>(
      s1, w2b, nullptr, DIM, FFN_DIM, nullptr, nullptr, nullptr, h2,
      counts, offsets, tok_list, wlist);
  final_kernel<<<4096, 256, 0, stream>>>(x_att, h2, slot_of, out0);
}

// Round 3
// 1234.824 us; speedup vs baseline: 2.1261x; 1.1151x over previous
//
#include <hip/hip_runtime.h>
#include <stdint.h>

#define S_LEN 2048
#define NB 2
#define DIM 1024
#define NHEAD 16
#define DHEAD 64
#define FFN_DIM 4096
#define NEXP 8
#define NTOK 4096  // S*B

typedef __attribute__((ext_vector_type(8))) short short8;
typedef __attribute__((ext_vector_type(4))) short short4v;
typedef __attribute__((ext_vector_type(4))) float f32x4;

__device__ __forceinline__ short f2bf(float f) {
  unsigned u = __float_as_uint(f);
  unsigned r = (u + 0x7FFFu + ((u >> 16) & 1u)) >> 16;
  return (short)(unsigned short)r;
}
__device__ __forceinline__ void async_ld16(const short* g, short* l) {
  __builtin_amdgcn_global_load_lds(
      (const __attribute__((address_space(1))) void*)g,
      (__attribute__((address_space(3))) void*)l, 16, 0, 0);
}

// ---------------- fp32 -> bf16 weight conversion (coalesced) ----------------
__global__ __launch_bounds__(256) void cvt_kernel(const float* __restrict__ src,
                                                  short* __restrict__ dst, int n) {
  int i = (blockIdx.x * 256 + threadIdx.x) * 8;
  if (i >= n) return;
  float4 a = *(const float4*)(src + i);
  float4 b = *(const float4*)(src + i + 4);
  short8 o;
  o[0] = f2bf(a.x); o[1] = f2bf(a.y); o[2] = f2bf(a.z); o[3] = f2bf(a.w);
  o[4] = f2bf(b.x); o[5] = f2bf(b.y); o[6] = f2bf(b.z); o[7] = f2bf(b.w);
  *(short8*)(dst + i) = o;
}

// ---------------- LayerNorm: fp32 in -> bf16 out ----------------
__global__ __launch_bounds__(256) void ln_kernel(const float* __restrict__ x,
                                                 const float* __restrict__ g,
                                                 const float* __restrict__ b,
                                                 short* __restrict__ out) {
  int t = blockIdx.x, tid = threadIdx.x;
  const float* row = x + (size_t)t * DIM;
  float4 v = *(const float4*)(row + tid * 4);
  __shared__ float sb1[4], sb2[4];
  float s = v.x + v.y + v.z + v.w;
  for (int off = 32; off; off >>= 1) s += __shfl_xor(s, off, 64);
  if ((tid & 63) == 0) sb1[tid >> 6] = s;
  __syncthreads();
  float mean = (sb1[0] + sb1[1] + sb1[2] + sb1[3]) * (1.0f / DIM);
  float d0 = v.x - mean, d1 = v.y - mean, d2 = v.z - mean, d3 = v.w - mean;
  float q = d0 * d0 + d1 * d1 + d2 * d2 + d3 * d3;
  for (int off = 32; off; off >>= 1) q += __shfl_xor(q, off, 64);
  if ((tid & 63) == 0) sb2[tid >> 6] = q;
  __syncthreads();
  float var = (sb2[0] + sb2[1] + sb2[2] + sb2[3]) * (1.0f / DIM);
  float rstd = rsqrtf(var + 1e-5f);
  int c = tid * 4;
  float4 gg = *(const float4*)(g + c);
  float4 bb = *(const float4*)(b + c);
  short4v o;
  o.x = f2bf(d0 * rstd * gg.x + bb.x);
  o.y = f2bf(d1 * rstd * gg.y + bb.y);
  o.z = f2bf(d2 * rstd * gg.z + bb.z);
  o.w = f2bf(d3 * rstd * gg.w + bb.w);
  *(short4v*)(out + (size_t)t * DIM + c) = o;
}

// ---------------- GEMM: C[M,N] = A[M,K](bf16) @ B[N,K](bf16)^T ---------------
// TMxTN tile, 4 waves as 2x2. XOR bank swizzle on LDS column chunks.
// EPI: 0=+bias->bf16(qkv)  1=+bias+resid->f32  4=*wrow->f32  5=silu(a1)*a3->bf16
template <int EPI, bool EXPERT, bool GATHER, bool DUAL, int TM, int TN>
__global__ __launch_bounds__(256, 2) void gemm_k(
    const short* __restrict__ A, const short* __restrict__ B1w,
    const short* __restrict__ B2w, int N, int K,
    const float* __restrict__ bias, const float* __restrict__ resid,
    short* __restrict__ outb, float* __restrict__ outf,
    const int* __restrict__ counts, const int* __restrict__ offsets,
    const int* __restrict__ tok_list, const float* __restrict__ wlist) {
  constexpr int TM2 = TM / 2, TN2 = TN / 2;
  constexpr int MI = TM / 32, NJ = TN / 32;  // per-wave 16-row / 16-col tiles
  constexpr int CA = TM / 64, CB = TN / 64;  // staging chunks per thread
  int nt = blockIdx.x, mt = blockIdx.y;
  int e = EXPERT ? blockIdx.z : 0;
  int cnt = 0, aoff = 0;
  if (EXPERT) {
    cnt = counts[e];
    if (mt * TM >= cnt) return;
    aoff = offsets[e];
  }
  const short* Be1 = B1w + (size_t)e * N * K;
  const short* Be3 = DUAL ? (B2w + (size_t)e * N * K) : nullptr;
  int m0 = mt * TM, n0 = nt * TN;
  int tid = threadIdx.x;
  int wave = tid >> 6, lane = tid & 63;
  int quad = lane >> 4, lr = lane & 15;
  int wr = wave >> 1, wc = wave & 1;

  extern __shared__ short smem[];
  short* As = smem;                 // TM x 32
  short* Bs1 = smem + TM * 32;      // TN x 32
  short* Bs3 = Bs1 + TN * 32;       // TN x 32 (DUAL)

  // staging: chunk q = c*256+tid; row=q>>2, kc=q&3; global col chunk kc^(row&3)
  const short* Ap[CA];
  const short* Bp[CB];
  const short* Cp[DUAL ? CB : 1];
#pragma unroll
  for (int c = 0; c < CA; c++) {
    int q = c * 256 + tid;
    int row = q >> 2, kc = q & 3;
    int kg = kc ^ (row & 3);
    size_t ar;
    if (GATHER) {
      int i0 = m0 + row; if (i0 > cnt - 1) i0 = cnt - 1;
      ar = (size_t)tok_list[aoff + i0];
    } else if (EXPERT) {
      int i0 = m0 + row; if (i0 > cnt - 1) i0 = cnt - 1;
      ar = (size_t)(aoff + i0);
    } else {
      ar = (size_t)(m0 + row);
    }
    Ap[c] = A + ar * K + kg * 8;
  }
#pragma unroll
  for (int c = 0; c < CB; c++) {
    int q = c * 256 + tid;
    int row = q >> 2, kc = q & 3;
    int kg = kc ^ (row & 3);
    Bp[c] = Be1 + (size_t)(n0 + row) * K + kg * 8;
    if (DUAL) Cp[c] = Be3 + (size_t)(n0 + row) * K + kg * 8;
  }

  f32x4 acc[MI][NJ];
  f32x4 acc3[DUAL ? MI : 1][DUAL ? NJ : 1];
#pragma unroll
  for (int i = 0; i < MI; i++)
#pragma unroll
    for (int j = 0; j < NJ; j++) acc[i][j] = (f32x4){0.f, 0.f, 0.f, 0.f};
  if (DUAL) {
#pragma unroll
    for (int i = 0; i < MI; i++)
#pragma unroll
      for (int j = 0; j < NJ; j++) acc3[i][j] = (f32x4){0.f, 0.f, 0.f, 0.f};
  }

  int sq = quad ^ (lr & 3);  // swizzled column chunk for fragment reads

  for (int k0 = 0; k0 < K; k0 += 32) {
#pragma unroll
    for (int c = 0; c < CA; c++)
      async_ld16(Ap[c] + k0, As + (c * 256 + tid) * 8);
#pragma unroll
    for (int c = 0; c < CB; c++)
      async_ld16(Bp[c] + k0, Bs1 + (c * 256 + tid) * 8);
    if (DUAL) {
#pragma unroll
      for (int c = 0; c < CB; c++)
        async_ld16(Cp[c] + k0, Bs3 + (c * 256 + tid) * 8);
    }
    __syncthreads();
    short8 af[MI], bf[NJ];
#pragma unroll
    for (int i = 0; i < MI; i++)
      af[i] = *(const short8*)&As[(wr * TM2 + i * 16 + lr) * 32 + sq * 8];
#pragma unroll
    for (int j = 0; j < NJ; j++)
      bf[j] = *(const short8*)&Bs1[(wc * TN2 + j * 16 + lr) * 32 + sq * 8];
#pragma unroll
    for (int i = 0; i < MI; i++)
#pragma unroll
      for (int j = 0; j < NJ; j++)
        acc[i][j] = __builtin_amdgcn_mfma_f32_16x16x32_bf16(af[i], bf[j], acc[i][j], 0, 0, 0);
    if (DUAL) {
      short8 cf[NJ];
#pragma unroll
      for (int j = 0; j < NJ; j++)
        cf[j] = *(const short8*)&Bs3[(wc * TN2 + j * 16 + lr) * 32 + sq * 8];
#pragma unroll
      for (int i = 0; i < MI; i++)
#pragma unroll
        for (int j = 0; j < NJ; j++)
          acc3[i][j] = __builtin_amdgcn_mfma_f32_16x16x32_bf16(af[i], cf[j], acc3[i][j], 0, 0, 0);
    }
    __syncthreads();
  }

#pragma unroll
  for (int i = 0; i < MI; i++) {
    int rbase = wr * TM2 + i * 16 + quad * 4;
#pragma unroll
    for (int j = 0; j < NJ; j++) {
      int c = n0 + wc * TN2 + j * 16 + lr;
#pragma unroll
      for (int r = 0; r < 4; r++) {
        int rl = rbase + r;
        float v = acc[i][j][r];
        if (EPI == 0) {
          int t = m0 + rl;
          outb[(size_t)t * N + c] = f2bf(v + bias[c]);
        } else if (EPI == 1) {
          int t = m0 + rl;
          size_t idx = (size_t)t * N + c;
          outf[idx] = v + bias[c] + resid[idx];
        } else if (EPI == 4) {
          int rg = m0 + rl;
          if (rg < cnt) {
            size_t slot = (size_t)(aoff + rg);
            outf[slot * N + c] = v * wlist[slot];
          }
        } else {  // 5: silu(acc)*acc3 -> bf16
          int rg = m0 + rl;
          if (rg < cnt) {
            float v3 = acc3[i][j][r];
            float sv = v / (1.0f + __expf(-v));
            outb[(size_t)(aoff + rg) * N + c] = f2bf(sv * v3);
          }
        }
      }
    }
  }
}

// ---------------- Flash attention: 4 waves x 16 q-rows per block -------------
__global__ __launch_bounds__(256) void attn_kernel(const short* __restrict__ qkv,
                                                   short* __restrict__ oa) {
  int qt = blockIdx.x;  // 0..31 (64 q rows each)
  int bh = blockIdx.y;  // b*16+h
  int b_ = bh >> 4, h = bh & 15;
  int tid = threadIdx.x, wave = tid >> 6, lane = tid & 63;
  int quad = lane >> 4, lr = lane & 15;

  __shared__ short Ks[32 * 72];
  __shared__ short Vt[64 * 40];
  __shared__ short Ps[4 * 16 * 40];

  int sq = qt * 64 + wave * 16 + lr;
  const short* qrow = qkv + (size_t)(sq * NB + b_) * 3072 + h * 64;
  short8 qa0 = *(const short8*)(qrow + quad * 8);
  short8 qa1 = *(const short8*)(qrow + 32 + quad * 8);

  f32x4 oacc[4];
#pragma unroll
  for (int n = 0; n < 4; n++) oacc[n] = (f32x4){0.f, 0.f, 0.f, 0.f};
  float mrow[4], lsum[4];
#pragma unroll
  for (int r = 0; r < 4; r++) { mrow[r] = -1e30f; lsum[r] = 0.f; }

  int krow = tid >> 3, kpart = tid & 7;
  const float scale = 0.125f;  // 1/sqrt(64)

  for (int kt = 0; kt < S_LEN / 32; kt++) {
    __syncthreads();
    int sk = kt * 32 + krow;
    const short* kr = qkv + (size_t)(sk * NB + b_) * 3072 + 1024 + h * 64 + kpart * 8;
    *(short8*)&Ks[krow * 72 + kpart * 8] = *(const short8*)kr;
    const short* vr = qkv + (size_t)(sk * NB + b_) * 3072 + 2048 + h * 64 + kpart * 8;
    short8 vv = *(const short8*)vr;
#pragma unroll
    for (int j = 0; j < 8; j++) Vt[(kpart * 8 + j) * 40 + krow] = vv[j];
    __syncthreads();

    f32x4 sc[2];
#pragma unroll
    for (int g = 0; g < 2; g++) {
      short8 kb0 = *(const short8*)&Ks[(g * 16 + lr) * 72 + quad * 8];
      short8 kb1 = *(const short8*)&Ks[(g * 16 + lr) * 72 + 32 + quad * 8];
      f32x4 z = (f32x4){0.f, 0.f, 0.f, 0.f};
      z = __builtin_amdgcn_mfma_f32_16x16x32_bf16(qa0, kb0, z, 0, 0, 0);
      z = __builtin_amdgcn_mfma_f32_16x16x32_bf16(qa1, kb1, z, 0, 0, 0);
      sc[g] = z;
    }
    float alpha[4];
#pragma unroll
    for (int r = 0; r < 4; r++) {
      float s0 = sc[0][r] * scale, s1 = sc[1][r] * scale;
      float mx = fmaxf(s0, s1);
      mx = fmaxf(mx, __shfl_xor(mx, 1, 64));
      mx = fmaxf(mx, __shfl_xor(mx, 2, 64));
      mx = fmaxf(mx, __shfl_xor(mx, 4, 64));
      mx = fmaxf(mx, __shfl_xor(mx, 8, 64));
      float mnew = fmaxf(mrow[r], mx);
      alpha[r] = __expf(mrow[r] - mnew);
      float p0 = __expf(s0 - mnew), p1 = __expf(s1 - mnew);
      sc[0][r] = p0; sc[1][r] = p1;
      float ps = p0 + p1;
      ps += __shfl_xor(ps, 1, 64);
      ps += __shfl_xor(ps, 2, 64);
      ps += __shfl_xor(ps, 4, 64);
      ps += __shfl_xor(ps, 8, 64);
      lsum[r] = lsum[r] * alpha[r] + ps;
      mrow[r] = mnew;
    }
#pragma unroll
    for (int n = 0; n < 4; n++)
#pragma unroll
      for (int r = 0; r < 4; r++) oacc[n][r] *= alpha[r];
    short* pw = Ps + wave * 16 * 40;
#pragma unroll
    for (int r = 0; r < 4; r++) {
      pw[(quad * 4 + r) * 40 + lr] = f2bf(sc[0][r]);
      pw[(quad * 4 + r) * 40 + 16 + lr] = f2bf(sc[1][r]);
    }
    __syncthreads();
    short8 pf = *(const short8*)&pw[lr * 40 + quad * 8];
#pragma unroll
    for (int n = 0; n < 4; n++) {
      short8 vf = *(const short8*)&Vt[(n * 16 + lr) * 40 + quad * 8];
      oacc[n] = __builtin_amdgcn_mfma_f32_16x16x32_bf16(pf, vf, oacc[n], 0, 0, 0);
    }
  }
#pragma unroll
  for (int r = 0; r < 4; r++) {
    int srow = qt * 64 + wave * 16 + quad * 4 + r;
    short* orow = oa + (size_t)(srow * NB + b_) * 1024 + h * 64;
    float inv = 1.0f / lsum[r];
#pragma unroll
    for (int n = 0; n < 4; n++) orow[n * 16 + lr] = f2bf(oacc[n][r] * inv);
  }
}

// ---------------- Router: full fp32 LN2 + gate logits + top-2 ----------------
__global__ __launch_bounds__(256) void router_kernel(
    const float* __restrict__ xa, const float* __restrict__ g2,
    const float* __restrict__ b2, const float* __restrict__ gate,
    float* __restrict__ logits_out, int* __restrict__ topi,
    float* __restrict__ topw, int* __restrict__ counts) {
  int t = blockIdx.x, tid = threadIdx.x;
  const float* row = xa + (size_t)t * DIM;
  float4 v = *(const float4*)(row + tid * 4);
  __shared__ float sb1[4], sb2[4];
  __shared__ float rede[4][8];
  float s = v.x + v.y + v.z + v.w;
  for (int off = 32; off; off >>= 1) s += __shfl_xor(s, off, 64);
  if ((tid & 63) == 0) sb1[tid >> 6] = s;
  __syncthreads();
  float mean = (sb1[0] + sb1[1] + sb1[2] + sb1[3]) * (1.0f / DIM);
  float d0 = v.x - mean, d1 = v.y - mean, d2 = v.z - mean, d3 = v.w - mean;
  float q = d0 * d0 + d1 * d1 + d2 * d2 + d3 * d3;
  for (int off = 32; off; off >>= 1) q += __shfl_xor(q, off, 64);
  if ((tid & 63) == 0) sb2[tid >> 6] = q;
  __syncthreads();
  float var = (sb2[0] + sb2[1] + sb2[2] + sb2[3]) * (1.0f / DIM);
  float rstd = rsqrtf(var + 1e-5f);
  int c = tid * 4;
  float4 gg = *(const float4*)(g2 + c);
  float4 bb = *(const float4*)(b2 + c);
  float h0 = d0 * rstd * gg.x + bb.x, h1 = d1 * rstd * gg.y + bb.y;
  float h2v = d2 * rstd * gg.z + bb.z, h3 = d3 * rstd * gg.w + bb.w;
  float lg[8];
#pragma unroll
  for (int e = 0; e < 8; e++) {
    float4 gw = *(const float4*)(gate + e * DIM + c);
    lg[e] = h0 * gw.x + h1 * gw.y + h2v * gw.z + h3 * gw.w;
  }
#pragma unroll
  for (int e = 0; e < 8; e++)
    for (int off = 32; off; off >>= 1) lg[e] += __shfl_xor(lg[e], off, 64);
  if ((tid & 63) == 0)
#pragma unroll
    for (int e = 0; e < 8; e++) rede[tid >> 6][e] = lg[e];
  __syncthreads();
  if (tid == 0) {
    float L[8];
#pragma unroll
    for (int e = 0; e < 8; e++)
      L[e] = rede[0][e] + rede[1][e] + rede[2][e] + rede[3][e];
#pragma unroll
    for (int e = 0; e < 8; e++) logits_out[(size_t)t * 8 + e] = L[e];
    int i1 = 0;
    for (int e = 1; e < 8; e++) if (L[e] > L[i1]) i1 = e;
    int i2 = (i1 == 0) ? 1 : 0;
    for (int e = 0; e < 8; e++) if (e != i1 && L[e] > L[i2]) i2 = e;
    float mx = fmaxf(L[i1], L[i2]);
    float p1 = __expf(L[i1] - mx), p2 = __expf(L[i2] - mx);
    float inv = 1.0f / (p1 + p2);
    topi[t * 2] = i1; topi[t * 2 + 1] = i2;
    topw[t * 2] = p1 * inv; topw[t * 2 + 1] = p2 * inv;
    atomicAdd(&counts[i1], 1);
    atomicAdd(&counts[i2], 1);
  }
}

__global__ void scan_kernel(const int* __restrict__ counts, int* __restrict__ offsets,
                            int* __restrict__ cursors) {
  if (threadIdx.x == 0) {
    int acc = 0;
    for (int e = 0; e < 8; e++) {
      offsets[e] = acc;
      cursors[e] = acc;
      acc += counts[e];
    }
  }
}

__global__ __launch_bounds__(256) void scatter_kernel(
    const int* __restrict__ topi, const float* __restrict__ topw,
    int* __restrict__ cursors, int* __restrict__ tok_list,
    float* __restrict__ wlist, int* __restrict__ slot_of) {
  int t = blockIdx.x * 256 + threadIdx.x;
  if (t >= NTOK) return;
#pragma unroll
  for (int k = 0; k < 2; k++) {
    int e = topi[t * 2 + k];
    int pos = atomicAdd(&cursors[e], 1);
    tok_list[pos] = t;
    wlist[pos] = topw[t * 2 + k];
    slot_of[t * 2 + k] = pos;
  }
}

__global__ __launch_bounds__(256) void final_kernel(
    const float* __restrict__ xa, const float* __restrict__ h2,
    const int* __restrict__ slot_of, float* __restrict__ out) {
  size_t i = ((size_t)blockIdx.x * 256 + threadIdx.x) * 4;
  int t = (int)(i >> 10);
  int c = (int)(i & 1023);
  float4 a = *(const float4*)(xa + i);
  int s0 = slot_of[t * 2], s1 = slot_of[t * 2 + 1];
  float4 m0 = *(const float4*)(h2 + (size_t)s0 * 1024 + c);
  float4 m1 = *(const float4*)(h2 + (size_t)s1 * 1024 + c);
  float4 o;
  o.x = a.x + m0.x + m1.x;
  o.y = a.y + m0.y + m1.y;
  o.z = a.z + m0.z + m1.z;
  o.w = a.w + m0.w + m1.w;
  *(float4*)(out + i) = o;
}

extern "C" void kernel_launch(void* const* d_in, const int* in_sizes, int n_in,
                              void* d_out, int out_size, void* d_ws, size_t ws_size,
                              hipStream_t stream) {
  const float* x = (const float*)d_in[0];
  const float* in_w = (const float*)d_in[1];
  const float* in_b = (const float*)d_in[2];
  const float* out_w = (const float*)d_in[3];
  const float* out_b = (const float*)d_in[4];
  const float* ln1g = (const float*)d_in[5];
  const float* ln1b = (const float*)d_in[6];
  const float* ln2g = (const float*)d_in[7];
  const float* ln2b = (const float*)d_in[8];
  const float* gate = (const float*)d_in[9];
  const float* w1 = (const float*)d_in[10];
  const float* w2 = (const float*)d_in[11];
  const float* w3 = (const float*)d_in[12];
  float* out0 = (float*)d_out;
  float* logits = out0 + (size_t)NTOK * DIM;

  char* ws = (char*)d_ws;
  const size_t MB = 1u << 20;
  short* w1b = (short*)(ws);                // [0,64)   dead after w1w3
  short* w3b = (short*)(ws + 64 * MB);      // [64,128) dead after w1w3
  short* w2b = (short*)(ws + 128 * MB);     // [128,192)
  short* in_wb = (short*)(ws + 192 * MB);   // [192,198)
  short* out_wb = (short*)(ws + 198 * MB);  // [198,200)
  short* x_ln1 = (short*)(ws + 200 * MB);   // dead after qkv   } inside s1
  short* qkv = (short*)(ws + 208 * MB);     // dead after attn  } region
  short* o_attn = (short*)(ws + 232 * MB);  // dead after outprj} (written later)
  short* s1 = (short*)(ws + 200 * MB);      // [200,264) written by w1w3
  float* h2 = (float*)(ws);                 // [0,32) overlays w1b (dead)
  float* x_att = (float*)(ws + 264 * MB);   // [264,280) live to end
  short* x_ln2 = (short*)(ws + 280 * MB);   // [280,288)
  char* ctrl = ws + 288 * MB;
  int* counts = (int*)ctrl;
  int* offsets = counts + 8;
  int* cursors = counts + 16;
  int* topi = (int*)(ctrl + 256);
  float* topw = (float*)(ctrl + 256 + 32 * 1024);
  int* slot_of = (int*)(ctrl + 256 + 64 * 1024);
  int* tok_list = (int*)(ctrl + 256 + 96 * 1024);
  float* wlist = (float*)(ctrl + 256 + 128 * 1024);

  hipMemsetAsync(counts, 0, 32, stream);
  cvt_kernel<<<(NEXP * FFN_DIM * DIM) / 8 / 256, 256, 0, stream>>>(w1, w1b, NEXP * FFN_DIM * DIM);
  cvt_kernel<<<(NEXP * FFN_DIM * DIM) / 8 / 256, 256, 0, stream>>>(w3, w3b, NEXP * FFN_DIM * DIM);
  cvt_kernel<<<(NEXP * FFN_DIM * DIM) / 8 / 256, 256, 0, stream>>>(w2, w2b, NEXP * DIM * FFN_DIM);
  cvt_kernel<<<(3 * DIM * DIM) / 8 / 256, 256, 0, stream>>>(in_w, in_wb, 3 * DIM * DIM);
  cvt_kernel<<<(DIM * DIM) / 8 / 256, 256, 0, stream>>>(out_w, out_wb, DIM * DIM);

  ln_kernel<<<NTOK, 256, 0, stream>>>(x, ln1g, ln1b, x_ln1);
  gemm_k<0, false, false, false, 128, 128><<<dim3(24, 32, 1), 256, 16384, stream>>>(
      x_ln1, in_wb, nullptr, 3072, 1024, in_b, nullptr, qkv, nullptr,
      nullptr, nullptr, nullptr, nullptr);
  attn_kernel<<<dim3(32, 32), 256, 0, stream>>>(qkv, o_attn);
  gemm_k<1, false, false, false, 128, 128><<<dim3(8, 32, 1), 256, 16384, stream>>>(
      o_attn, out_wb, nullptr, 1024, 1024, out_b, x, nullptr, x_att,
      nullptr, nullptr, nullptr, nullptr);
  ln_kernel<<<NTOK, 256, 0, stream>>>(x_att, ln2g, ln2b, x_ln2);
  router_kernel<<<NTOK, 256, 0, stream>>>(x_att, ln2g, ln2b, gate, logits, topi, topw, counts);
  scan_kernel<<<1, 64, 0, stream>>>(counts, offsets, cursors);
  scatter_kernel<<<16, 256, 0, stream>>>(topi, topw, cursors, tok_list, wlist, slot_of);
  // fused w1/w3: s1 = silu(x@w1^T) * (x@w3^T); 128x64 tile (acc fits 2 waves/SIMD)
  gemm_k<5, true, true, true, 128, 64><<<dim3(64, 32, 8), 256, 16384, stream>>>(
      x_ln2, w1b, w3b, FFN_DIM, DIM, nullptr, nullptr, s1, nullptr,
      counts, offsets, tok_list, wlist);
  // w2: h2 = (s1 @ w2^T) * combine_weight; 64x128 tile (more blocks, K=4096)
  gemm_k<4, true, false, false, 64, 128><<<dim3(8, 64, 8), 256, 12288, stream>>>(
      s1, w2b, nullptr, DIM, FFN_DIM, nullptr, nullptr, nullptr, h2,
      counts, offsets, tok_list, wlist);
  final_kernel<<<4096, 256, 0, stream>>>(x_att, h2, slot_of, out0);
}

// Round 4
// 1138.152 us; speedup vs baseline: 2.3067x; 1.0849x over previous
//
#include <hip/hip_runtime.h>
#include <stdint.h>

#define S_LEN 2048
#define NB 2
#define DIM 1024
#define NHEAD 16
#define DHEAD 64
#define FFN_DIM 4096
#define NEXP 8
#define NTOK 4096  // S*B

typedef __attribute__((ext_vector_type(8))) short short8;
typedef __attribute__((ext_vector_type(4))) short short4v;
typedef __attribute__((ext_vector_type(4))) float f32x4;

__device__ __forceinline__ short f2bf(float f) {
  unsigned u = __float_as_uint(f);
  unsigned r = (u + 0x7FFFu + ((u >> 16) & 1u)) >> 16;
  return (short)(unsigned short)r;
}
__device__ __forceinline__ void async_ld16(const short* g, short* l) {
  __builtin_amdgcn_global_load_lds(
      (const __attribute__((address_space(1))) void*)g,
      (__attribute__((address_space(3))) void*)l, 16, 0, 0);
}

// ---------------- fp32 -> bf16 weight conversion (coalesced) ----------------
__global__ __launch_bounds__(256) void cvt_kernel(const float* __restrict__ src,
                                                  short* __restrict__ dst, int n) {
  int i = (blockIdx.x * 256 + threadIdx.x) * 8;
  if (i >= n) return;
  float4 a = *(const float4*)(src + i);
  float4 b = *(const float4*)(src + i + 4);
  short8 o;
  o[0] = f2bf(a.x); o[1] = f2bf(a.y); o[2] = f2bf(a.z); o[3] = f2bf(a.w);
  o[4] = f2bf(b.x); o[5] = f2bf(b.y); o[6] = f2bf(b.z); o[7] = f2bf(b.w);
  *(short8*)(dst + i) = o;
}

// ---------------- LayerNorm: fp32 in -> bf16 out ----------------
__global__ __launch_bounds__(256) void ln_kernel(const float* __restrict__ x,
                                                 const float* __restrict__ g,
                                                 const float* __restrict__ b,
                                                 short* __restrict__ out) {
  int t = blockIdx.x, tid = threadIdx.x;
  const float* row = x + (size_t)t * DIM;
  float4 v = *(const float4*)(row + tid * 4);
  __shared__ float sb1[4], sb2[4];
  float s = v.x + v.y + v.z + v.w;
  for (int off = 32; off; off >>= 1) s += __shfl_xor(s, off, 64);
  if ((tid & 63) == 0) sb1[tid >> 6] = s;
  __syncthreads();
  float mean = (sb1[0] + sb1[1] + sb1[2] + sb1[3]) * (1.0f / DIM);
  float d0 = v.x - mean, d1 = v.y - mean, d2 = v.z - mean, d3 = v.w - mean;
  float q = d0 * d0 + d1 * d1 + d2 * d2 + d3 * d3;
  for (int off = 32; off; off >>= 1) q += __shfl_xor(q, off, 64);
  if ((tid & 63) == 0) sb2[tid >> 6] = q;
  __syncthreads();
  float var = (sb2[0] + sb2[1] + sb2[2] + sb2[3]) * (1.0f / DIM);
  float rstd = rsqrtf(var + 1e-5f);
  int c = tid * 4;
  float4 gg = *(const float4*)(g + c);
  float4 bb = *(const float4*)(b + c);
  short4v o;
  o.x = f2bf(d0 * rstd * gg.x + bb.x);
  o.y = f2bf(d1 * rstd * gg.y + bb.y);
  o.z = f2bf(d2 * rstd * gg.z + bb.z);
  o.w = f2bf(d3 * rstd * gg.w + bb.w);
  *(short4v*)(out + (size_t)t * DIM + c) = o;
}

// ---------------- GEMM: C[M,N] = A[M,K](bf16) @ B[N,K](bf16)^T ---------------
// TMxTN tile, 4 waves as 2x2. XOR bank swizzle on LDS column chunks.
// EPI: 0=+bias->bf16(qkv)  1=+bias+resid->f32  4=*wrow->f32  5=silu(a1)*a3->bf16
template <int EPI, bool EXPERT, bool GATHER, bool DUAL, int TM, int TN>
__global__ __launch_bounds__(256, 2) void gemm_k(
    const short* __restrict__ A, const short* __restrict__ B1w,
    const short* __restrict__ B2w, int N, int K,
    const float* __restrict__ bias, const float* __restrict__ resid,
    short* __restrict__ outb, float* __restrict__ outf,
    const int* __restrict__ counts, const int* __restrict__ offsets,
    const int* __restrict__ tok_list, const float* __restrict__ wlist) {
  constexpr int TM2 = TM / 2, TN2 = TN / 2;
  constexpr int MI = TM / 32, NJ = TN / 32;
  constexpr int CA = TM / 64, CB = TN / 64;
  int nt = blockIdx.x, mt = blockIdx.y;
  int e = EXPERT ? blockIdx.z : 0;
  int cnt = 0, aoff = 0;
  if (EXPERT) {
    cnt = counts[e];
    if (mt * TM >= cnt) return;
    aoff = offsets[e];
  }
  const short* Be1 = B1w + (size_t)e * N * K;
  const short* Be3 = DUAL ? (B2w + (size_t)e * N * K) : nullptr;
  int m0 = mt * TM, n0 = nt * TN;
  int tid = threadIdx.x;
  int wave = tid >> 6, lane = tid & 63;
  int quad = lane >> 4, lr = lane & 15;
  int wr = wave >> 1, wc = wave & 1;

  extern __shared__ short smem[];
  short* As = smem;
  short* Bs1 = smem + TM * 32;
  short* Bs3 = Bs1 + TN * 32;

  const short* Ap[CA];
  const short* Bp[CB];
  const short* Cp[DUAL ? CB : 1];
#pragma unroll
  for (int c = 0; c < CA; c++) {
    int q = c * 256 + tid;
    int row = q >> 2, kc = q & 3;
    int kg = kc ^ (row & 3);
    size_t ar;
    if (GATHER) {
      int i0 = m0 + row; if (i0 > cnt - 1) i0 = cnt - 1;
      ar = (size_t)tok_list[aoff + i0];
    } else if (EXPERT) {
      int i0 = m0 + row; if (i0 > cnt - 1) i0 = cnt - 1;
      ar = (size_t)(aoff + i0);
    } else {
      ar = (size_t)(m0 + row);
    }
    Ap[c] = A + ar * K + kg * 8;
  }
#pragma unroll
  for (int c = 0; c < CB; c++) {
    int q = c * 256 + tid;
    int row = q >> 2, kc = q & 3;
    int kg = kc ^ (row & 3);
    Bp[c] = Be1 + (size_t)(n0 + row) * K + kg * 8;
    if (DUAL) Cp[c] = Be3 + (size_t)(n0 + row) * K + kg * 8;
  }

  f32x4 acc[MI][NJ];
  f32x4 acc3[DUAL ? MI : 1][DUAL ? NJ : 1];
#pragma unroll
  for (int i = 0; i < MI; i++)
#pragma unroll
    for (int j = 0; j < NJ; j++) acc[i][j] = (f32x4){0.f, 0.f, 0.f, 0.f};
  if (DUAL) {
#pragma unroll
    for (int i = 0; i < MI; i++)
#pragma unroll
      for (int j = 0; j < NJ; j++) acc3[i][j] = (f32x4){0.f, 0.f, 0.f, 0.f};
  }

  int sq = quad ^ (lr & 3);

  for (int k0 = 0; k0 < K; k0 += 32) {
#pragma unroll
    for (int c = 0; c < CA; c++)
      async_ld16(Ap[c] + k0, As + (c * 256 + tid) * 8);
#pragma unroll
    for (int c = 0; c < CB; c++)
      async_ld16(Bp[c] + k0, Bs1 + (c * 256 + tid) * 8);
    if (DUAL) {
#pragma unroll
      for (int c = 0; c < CB; c++)
        async_ld16(Cp[c] + k0, Bs3 + (c * 256 + tid) * 8);
    }
    __syncthreads();
    short8 af[MI], bf[NJ];
#pragma unroll
    for (int i = 0; i < MI; i++)
      af[i] = *(const short8*)&As[(wr * TM2 + i * 16 + lr) * 32 + sq * 8];
#pragma unroll
    for (int j = 0; j < NJ; j++)
      bf[j] = *(const short8*)&Bs1[(wc * TN2 + j * 16 + lr) * 32 + sq * 8];
#pragma unroll
    for (int i = 0; i < MI; i++)
#pragma unroll
      for (int j = 0; j < NJ; j++)
        acc[i][j] = __builtin_amdgcn_mfma_f32_16x16x32_bf16(af[i], bf[j], acc[i][j], 0, 0, 0);
    if (DUAL) {
      short8 cf[NJ];
#pragma unroll
      for (int j = 0; j < NJ; j++)
        cf[j] = *(const short8*)&Bs3[(wc * TN2 + j * 16 + lr) * 32 + sq * 8];
#pragma unroll
      for (int i = 0; i < MI; i++)
#pragma unroll
        for (int j = 0; j < NJ; j++)
          acc3[i][j] = __builtin_amdgcn_mfma_f32_16x16x32_bf16(af[i], cf[j], acc3[i][j], 0, 0, 0);
    }
    __syncthreads();
  }

#pragma unroll
  for (int i = 0; i < MI; i++) {
    int rbase = wr * TM2 + i * 16 + quad * 4;
#pragma unroll
    for (int j = 0; j < NJ; j++) {
      int c = n0 + wc * TN2 + j * 16 + lr;
#pragma unroll
      for (int r = 0; r < 4; r++) {
        int rl = rbase + r;
        float v = acc[i][j][r];
        if (EPI == 0) {
          int t = m0 + rl;
          outb[(size_t)t * N + c] = f2bf(v + bias[c]);
        } else if (EPI == 1) {
          int t = m0 + rl;
          size_t idx = (size_t)t * N + c;
          outf[idx] = v + bias[c] + resid[idx];
        } else if (EPI == 4) {
          int rg = m0 + rl;
          if (rg < cnt) {
            size_t slot = (size_t)(aoff + rg);
            outf[slot * N + c] = v * wlist[slot];
          }
        } else {  // 5: silu(acc)*acc3 -> bf16
          int rg = m0 + rl;
          if (rg < cnt) {
            float v3 = acc3[i][j][r];
            float sv = v / (1.0f + __expf(-v));
            outb[(size_t)(aoff + rg) * N + c] = f2bf(sv * v3);
          }
        }
      }
    }
  }
}

// ---------------- V transpose: qkv V-part -> vt[b][h][dh][seq] ---------------
__global__ __launch_bounds__(256) void vtrans_kernel(const short* __restrict__ qkv,
                                                     short* __restrict__ vt) {
  int st = blockIdx.x;  // seq tile (64)
  int bh = blockIdx.y;
  int b_ = bh >> 4, h = bh & 15;
  int tid = threadIdx.x;
  __shared__ short t[64 * 72];  // [dh][seq], pitch 72
#pragma unroll
  for (int c = 0; c < 2; c++) {
    int q = c * 256 + tid;
    int seq = q >> 3, dhc = q & 7;
    int sk = st * 64 + seq;
    short8 v = *(const short8*)(qkv + (size_t)(sk * NB + b_) * 3072 + 2048 + h * 64 + dhc * 8);
#pragma unroll
    for (int k = 0; k < 8; k++) t[(dhc * 8 + k) * 72 + seq] = v[k];
  }
  __syncthreads();
#pragma unroll
  for (int c = 0; c < 2; c++) {
    int q = c * 256 + tid;
    int dh = q >> 3, sc_ = q & 7;
    short8 o = *(const short8*)&t[dh * 72 + sc_ * 8];
    *(short8*)(vt + ((size_t)bh * 64 + dh) * 2048 + st * 64 + sc_ * 8) = o;
  }
}

// ------- Flash attention: 4 waves x 16 q-rows, K-tile 64, async staging ------
__global__ __launch_bounds__(256) void attn_kernel(const short* __restrict__ qkv,
                                                   const short* __restrict__ vt,
                                                   short* __restrict__ oa) {
  int qt = blockIdx.x;  // 0..31
  int bh = blockIdx.y;  // b*16+h
  int b_ = bh >> 4, h = bh & 15;
  int tid = threadIdx.x, wave = tid >> 6, lane = tid & 63;
  int quad = lane >> 4, lr = lane & 15;
  int swz = lr & 7;

  __shared__ short Ks[64 * 64];  // [seq][dh], chunk-swizzled
  __shared__ short Vs[64 * 64];  // [dh][seq], chunk-swizzled
  __shared__ short Ps[4 * 16 * 64];

  int sq = qt * 64 + wave * 16 + lr;
  const short* qrow = qkv + (size_t)(sq * NB + b_) * 3072 + h * 64;
  short8 qa0 = *(const short8*)(qrow + quad * 8);
  short8 qa1 = *(const short8*)(qrow + 32 + quad * 8);

  // staging sources: chunk q = c*256+tid; row=q>>3, lds chunk=q&7,
  // global chunk = (q&7)^(row&7)  (XOR swizzle baked into source address)
  const short* ksrc[2];
  const short* vsrc[2];
#pragma unroll
  for (int c = 0; c < 2; c++) {
    int q = c * 256 + tid;
    int row = q >> 3, cl = q & 7;
    int cg = cl ^ (row & 7);
    ksrc[c] = qkv + (size_t)(row * NB + b_) * 3072 + 1024 + h * 64 + cg * 8;
    vsrc[c] = vt + ((size_t)bh * 64 + row) * 2048 + cg * 8;
  }

  f32x4 oacc[4];
#pragma unroll
  for (int n = 0; n < 4; n++) oacc[n] = (f32x4){0.f, 0.f, 0.f, 0.f};
  float mrow[4], lsum[4];
#pragma unroll
  for (int r = 0; r < 4; r++) { mrow[r] = -1e30f; lsum[r] = 0.f; }

  const float scale = 0.125f;  // 1/sqrt(64)

  for (int kt = 0; kt < S_LEN / 64; kt++) {
    int seq0 = kt * 64;
#pragma unroll
    for (int c = 0; c < 2; c++) {
      async_ld16(ksrc[c] + (size_t)seq0 * (NB * 3072), Ks + (c * 256 + tid) * 8);
      async_ld16(vsrc[c] + seq0, Vs + (c * 256 + tid) * 8);
    }
    __syncthreads();

    f32x4 sc[4];
#pragma unroll
    for (int g = 0; g < 4; g++) {
      short8 kb0 = *(const short8*)&Ks[(g * 16 + lr) * 64 + (quad ^ swz) * 8];
      short8 kb1 = *(const short8*)&Ks[(g * 16 + lr) * 64 + ((4 + quad) ^ swz) * 8];
      f32x4 z = (f32x4){0.f, 0.f, 0.f, 0.f};
      z = __builtin_amdgcn_mfma_f32_16x16x32_bf16(qa0, kb0, z, 0, 0, 0);
      z = __builtin_amdgcn_mfma_f32_16x16x32_bf16(qa1, kb1, z, 0, 0, 0);
      sc[g] = z;
    }
#pragma unroll
    for (int r = 0; r < 4; r++) {
      float s0 = sc[0][r] * scale, s1 = sc[1][r] * scale;
      float s2 = sc[2][r] * scale, s3 = sc[3][r] * scale;
      float mx = fmaxf(fmaxf(s0, s1), fmaxf(s2, s3));
      mx = fmaxf(mx, __shfl_xor(mx, 1, 64));
      mx = fmaxf(mx, __shfl_xor(mx, 2, 64));
      mx = fmaxf(mx, __shfl_xor(mx, 4, 64));
      mx = fmaxf(mx, __shfl_xor(mx, 8, 64));
      float mnew = fmaxf(mrow[r], mx);
      float alpha = __expf(mrow[r] - mnew);
      float p0 = __expf(s0 - mnew), p1 = __expf(s1 - mnew);
      float p2 = __expf(s2 - mnew), p3 = __expf(s3 - mnew);
      sc[0][r] = p0; sc[1][r] = p1; sc[2][r] = p2; sc[3][r] = p3;
      float ps = (p0 + p1) + (p2 + p3);
      ps += __shfl_xor(ps, 1, 64);
      ps += __shfl_xor(ps, 2, 64);
      ps += __shfl_xor(ps, 4, 64);
      ps += __shfl_xor(ps, 8, 64);
      lsum[r] = lsum[r] * alpha + ps;
      mrow[r] = mnew;
#pragma unroll
      for (int n = 0; n < 4; n++) oacc[n][r] *= alpha;
    }
    // write P (own wave region, chunk-swizzled); wave-internal DS order is safe
    short* pw = Ps + wave * 16 * 64;
#pragma unroll
    for (int r = 0; r < 4; r++) {
      int row = quad * 4 + r;
#pragma unroll
      for (int g = 0; g < 4; g++) {
        int cl = (g * 2 + (lr >> 3)) ^ (row & 7);
        pw[row * 64 + cl * 8 + (lr & 7)] = f2bf(sc[g][r]);
      }
    }
    short8 pf0 = *(const short8*)&pw[lr * 64 + (quad ^ swz) * 8];
    short8 pf1 = *(const short8*)&pw[lr * 64 + ((4 + quad) ^ swz) * 8];
#pragma unroll
    for (int n = 0; n < 4; n++) {
      short8 vf0 = *(const short8*)&Vs[(n * 16 + lr) * 64 + (quad ^ swz) * 8];
      short8 vf1 = *(const short8*)&Vs[(n * 16 + lr) * 64 + ((4 + quad) ^ swz) * 8];
      oacc[n] = __builtin_amdgcn_mfma_f32_16x16x32_bf16(pf0, vf0, oacc[n], 0, 0, 0);
      oacc[n] = __builtin_amdgcn_mfma_f32_16x16x32_bf16(pf1, vf1, oacc[n], 0, 0, 0);
    }
    __syncthreads();
  }
#pragma unroll
  for (int r = 0; r < 4; r++) {
    int srow = qt * 64 + wave * 16 + quad * 4 + r;
    short* orow = oa + (size_t)(srow * NB + b_) * 1024 + h * 64;
    float inv = 1.0f / lsum[r];
#pragma unroll
    for (int n = 0; n < 4; n++) orow[n * 16 + lr] = f2bf(oacc[n][r] * inv);
  }
}

// ---------------- Router: full fp32 LN2 + gate logits + top-2 ----------------
__global__ __launch_bounds__(256) void router_kernel(
    const float* __restrict__ xa, const float* __restrict__ g2,
    const float* __restrict__ b2, const float* __restrict__ gate,
    float* __restrict__ logits_out, int* __restrict__ topi,
    float* __restrict__ topw, int* __restrict__ counts) {
  int t = blockIdx.x, tid = threadIdx.x;
  const float* row = xa + (size_t)t * DIM;
  float4 v = *(const float4*)(row + tid * 4);
  __shared__ float sb1[4], sb2[4];
  __shared__ float rede[4][8];
  float s = v.x + v.y + v.z + v.w;
  for (int off = 32; off; off >>= 1) s += __shfl_xor(s, off, 64);
  if ((tid & 63) == 0) sb1[tid >> 6] = s;
  __syncthreads();
  float mean = (sb1[0] + sb1[1] + sb1[2] + sb1[3]) * (1.0f / DIM);
  float d0 = v.x - mean, d1 = v.y - mean, d2 = v.z - mean, d3 = v.w - mean;
  float q = d0 * d0 + d1 * d1 + d2 * d2 + d3 * d3;
  for (int off = 32; off; off >>= 1) q += __shfl_xor(q, off, 64);
  if ((tid & 63) == 0) sb2[tid >> 6] = q;
  __syncthreads();
  float var = (sb2[0] + sb2[1] + sb2[2] + sb2[3]) * (1.0f / DIM);
  float rstd = rsqrtf(var + 1e-5f);
  int c = tid * 4;
  float4 gg = *(const float4*)(g2 + c);
  float4 bb = *(const float4*)(b2 + c);
  float h0 = d0 * rstd * gg.x + bb.x, h1 = d1 * rstd * gg.y + bb.y;
  float h2v = d2 * rstd * gg.z + bb.z, h3 = d3 * rstd * gg.w + bb.w;
  float lg[8];
#pragma unroll
  for (int e = 0; e < 8; e++) {
    float4 gw = *(const float4*)(gate + e * DIM + c);
    lg[e] = h0 * gw.x + h1 * gw.y + h2v * gw.z + h3 * gw.w;
  }
#pragma unroll
  for (int e = 0; e < 8; e++)
    for (int off = 32; off; off >>= 1) lg[e] += __shfl_xor(lg[e], off, 64);
  if ((tid & 63) == 0)
#pragma unroll
    for (int e = 0; e < 8; e++) rede[tid >> 6][e] = lg[e];
  __syncthreads();
  if (tid == 0) {
    float L[8];
#pragma unroll
    for (int e = 0; e < 8; e++)
      L[e] = rede[0][e] + rede[1][e] + rede[2][e] + rede[3][e];
#pragma unroll
    for (int e = 0; e < 8; e++) logits_out[(size_t)t * 8 + e] = L[e];
    int i1 = 0;
    for (int e = 1; e < 8; e++) if (L[e] > L[i1]) i1 = e;
    int i2 = (i1 == 0) ? 1 : 0;
    for (int e = 0; e < 8; e++) if (e != i1 && L[e] > L[i2]) i2 = e;
    float mx = fmaxf(L[i1], L[i2]);
    float p1 = __expf(L[i1] - mx), p2 = __expf(L[i2] - mx);
    float inv = 1.0f / (p1 + p2);
    topi[t * 2] = i1; topi[t * 2 + 1] = i2;
    topw[t * 2] = p1 * inv; topw[t * 2 + 1] = p2 * inv;
    atomicAdd(&counts[i1], 1);
    atomicAdd(&counts[i2], 1);
  }
}

__global__ void scan_kernel(const int* __restrict__ counts, int* __restrict__ offsets,
                            int* __restrict__ cursors) {
  if (threadIdx.x == 0) {
    int acc = 0;
    for (int e = 0; e < 8; e++) {
      offsets[e] = acc;
      cursors[e] = acc;
      acc += counts[e];
    }
  }
}

__global__ __launch_bounds__(256) void scatter_kernel(
    const int* __restrict__ topi, const float* __restrict__ topw,
    int* __restrict__ cursors, int* __restrict__ tok_list,
    float* __restrict__ wlist, int* __restrict__ slot_of) {
  int t = blockIdx.x * 256 + threadIdx.x;
  if (t >= NTOK) return;
#pragma unroll
  for (int k = 0; k < 2; k++) {
    int e = topi[t * 2 + k];
    int pos = atomicAdd(&cursors[e], 1);
    tok_list[pos] = t;
    wlist[pos] = topw[t * 2 + k];
    slot_of[t * 2 + k] = pos;
  }
}

__global__ __launch_bounds__(256) void final_kernel(
    const float* __restrict__ xa, const float* __restrict__ h2,
    const int* __restrict__ slot_of, float* __restrict__ out) {
  size_t i = ((size_t)blockIdx.x * 256 + threadIdx.x) * 4;
  int t = (int)(i >> 10);
  int c = (int)(i & 1023);
  float4 a = *(const float4*)(xa + i);
  int s0 = slot_of[t * 2], s1 = slot_of[t * 2 + 1];
  float4 m0 = *(const float4*)(h2 + (size_t)s0 * 1024 + c);
  float4 m1 = *(const float4*)(h2 + (size_t)s1 * 1024 + c);
  float4 o;
  o.x = a.x + m0.x + m1.x;
  o.y = a.y + m0.y + m1.y;
  o.z = a.z + m0.z + m1.z;
  o.w = a.w + m0.w + m1.w;
  *(float4*)(out + i) = o;
}

extern "C" void kernel_launch(void* const* d_in, const int* in_sizes, int n_in,
                              void* d_out, int out_size, void* d_ws, size_t ws_size,
                              hipStream_t stream) {
  const float* x = (const float*)d_in[0];
  const float* in_w = (const float*)d_in[1];
  const float* in_b = (const float*)d_in[2];
  const float* out_w = (const float*)d_in[3];
  const float* out_b = (const float*)d_in[4];
  const float* ln1g = (const float*)d_in[5];
  const float* ln1b = (const float*)d_in[6];
  const float* ln2g = (const float*)d_in[7];
  const float* ln2b = (const float*)d_in[8];
  const float* gate = (const float*)d_in[9];
  const float* w1 = (const float*)d_in[10];
  const float* w2 = (const float*)d_in[11];
  const float* w3 = (const float*)d_in[12];
  float* out0 = (float*)d_out;
  float* logits = out0 + (size_t)NTOK * DIM;

  char* ws = (char*)d_ws;
  const size_t MB = 1u << 20;
  short* w1b = (short*)(ws);                // [0,64)   dead after w1w3
  short* w3b = (short*)(ws + 64 * MB);      // [64,128) dead after w1w3
  short* w2b = (short*)(ws + 128 * MB);     // [128,192)
  short* in_wb = (short*)(ws + 192 * MB);   // [192,198)
  short* out_wb = (short*)(ws + 198 * MB);  // [198,200)
  short* x_ln1 = (short*)(ws + 200 * MB);   // dead after qkv   } inside s1
  short* qkv = (short*)(ws + 208 * MB);     // dead after attn  } region
  short* o_attn = (short*)(ws + 232 * MB);  // dead after outprj}
  short* vt = (short*)(ws + 240 * MB);      // [240,248) V^T, dead after attn
  short* s1 = (short*)(ws + 200 * MB);      // [200,264) written by w1w3
  float* h2 = (float*)(ws);                 // [0,32) overlays w1b (dead)
  float* x_att = (float*)(ws + 264 * MB);   // [264,280) live to end
  short* x_ln2 = (short*)(ws + 280 * MB);   // [280,288)
  char* ctrl = ws + 288 * MB;
  int* counts = (int*)ctrl;
  int* offsets = counts + 8;
  int* cursors = counts + 16;
  int* topi = (int*)(ctrl + 256);
  float* topw = (float*)(ctrl + 256 + 32 * 1024);
  int* slot_of = (int*)(ctrl + 256 + 64 * 1024);
  int* tok_list = (int*)(ctrl + 256 + 96 * 1024);
  float* wlist = (float*)(ctrl + 256 + 128 * 1024);

  hipMemsetAsync(counts, 0, 32, stream);
  cvt_kernel<<<(NEXP * FFN_DIM * DIM) / 8 / 256, 256, 0, stream>>>(w1, w1b, NEXP * FFN_DIM * DIM);
  cvt_kernel<<<(NEXP * FFN_DIM * DIM) / 8 / 256, 256, 0, stream>>>(w3, w3b, NEXP * FFN_DIM * DIM);
  cvt_kernel<<<(NEXP * FFN_DIM * DIM) / 8 / 256, 256, 0, stream>>>(w2, w2b, NEXP * DIM * FFN_DIM);
  cvt_kernel<<<(3 * DIM * DIM) / 8 / 256, 256, 0, stream>>>(in_w, in_wb, 3 * DIM * DIM);
  cvt_kernel<<<(DIM * DIM) / 8 / 256, 256, 0, stream>>>(out_w, out_wb, DIM * DIM);

  ln_kernel<<<NTOK, 256, 0, stream>>>(x, ln1g, ln1b, x_ln1);
  gemm_k<0, false, false, false, 128, 128><<<dim3(24, 32, 1), 256, 16384, stream>>>(
      x_ln1, in_wb, nullptr, 3072, 1024, in_b, nullptr, qkv, nullptr,
      nullptr, nullptr, nullptr, nullptr);
  vtrans_kernel<<<dim3(32, 32), 256, 0, stream>>>(qkv, vt);
  attn_kernel<<<dim3(32, 32), 256, 0, stream>>>(qkv, vt, o_attn);
  gemm_k<1, false, false, false, 128, 128><<<dim3(8, 32, 1), 256, 16384, stream>>>(
      o_attn, out_wb, nullptr, 1024, 1024, out_b, x, nullptr, x_att,
      nullptr, nullptr, nullptr, nullptr);
  ln_kernel<<<NTOK, 256, 0, stream>>>(x_att, ln2g, ln2b, x_ln2);
  router_kernel<<<NTOK, 256, 0, stream>>>(x_att, ln2g, ln2b, gate, logits, topi, topw, counts);
  scan_kernel<<<1, 64, 0, stream>>>(counts, offsets, cursors);
  scatter_kernel<<<16, 256, 0, stream>>>(topi, topw, cursors, tok_list, wlist, slot_of);
  gemm_k<5, true, true, true, 128, 64><<<dim3(64, 32, 8), 256, 16384, stream>>>(
      x_ln2, w1b, w3b, FFN_DIM, DIM, nullptr, nullptr, s1, nullptr,
      counts, offsets, tok_list, wlist);
  gemm_k<4, true, false, false, 64, 128><<<dim3(8, 64, 8), 256, 12288, stream>>>(
      s1, w2b, nullptr, DIM, FFN_DIM, nullptr, nullptr, nullptr, h2,
      counts, offsets, tok_list, wlist);
  final_kernel<<<4096, 256, 0, stream>>>(x_att, h2, slot_of, out0);
}

// Round 5
// 1042.280 us; speedup vs baseline: 2.5189x; 1.0920x over previous
//
#include <hip/hip_runtime.h>
#include <stdint.h>

#define S_LEN 2048
#define NB 2
#define DIM 1024
#define NHEAD 16
#define DHEAD 64
#define FFN_DIM 4096
#define NEXP 8
#define NTOK 4096  // S*B

typedef __attribute__((ext_vector_type(8))) short short8;
typedef __attribute__((ext_vector_type(4))) short short4v;
typedef __attribute__((ext_vector_type(4))) float f32x4;

__device__ __forceinline__ short f2bf(float f) {
  unsigned u = __float_as_uint(f);
  unsigned r = (u + 0x7FFFu + ((u >> 16) & 1u)) >> 16;
  return (short)(unsigned short)r;
}
__device__ __forceinline__ void async_ld16(const short* g, short* l) {
  __builtin_amdgcn_global_load_lds(
      (const __attribute__((address_space(1))) void*)g,
      (__attribute__((address_space(3))) void*)l, 16, 0, 0);
}

// ---------------- fp32 -> bf16 weight conversion (coalesced) ----------------
__global__ __launch_bounds__(256) void cvt_kernel(const float* __restrict__ src,
                                                  short* __restrict__ dst, int n) {
  int i = (blockIdx.x * 256 + threadIdx.x) * 8;
  if (i >= n) return;
  float4 a = *(const float4*)(src + i);
  float4 b = *(const float4*)(src + i + 4);
  short8 o;
  o[0] = f2bf(a.x); o[1] = f2bf(a.y); o[2] = f2bf(a.z); o[3] = f2bf(a.w);
  o[4] = f2bf(b.x); o[5] = f2bf(b.y); o[6] = f2bf(b.z); o[7] = f2bf(b.w);
  *(short8*)(dst + i) = o;
}

// ---------------- LayerNorm: fp32 in -> bf16 out ----------------
__global__ __launch_bounds__(256) void ln_kernel(const float* __restrict__ x,
                                                 const float* __restrict__ g,
                                                 const float* __restrict__ b,
                                                 short* __restrict__ out) {
  int t = blockIdx.x, tid = threadIdx.x;
  const float* row = x + (size_t)t * DIM;
  float4 v = *(const float4*)(row + tid * 4);
  __shared__ float sb1[4], sb2[4];
  float s = v.x + v.y + v.z + v.w;
  for (int off = 32; off; off >>= 1) s += __shfl_xor(s, off, 64);
  if ((tid & 63) == 0) sb1[tid >> 6] = s;
  __syncthreads();
  float mean = (sb1[0] + sb1[1] + sb1[2] + sb1[3]) * (1.0f / DIM);
  float d0 = v.x - mean, d1 = v.y - mean, d2 = v.z - mean, d3 = v.w - mean;
  float q = d0 * d0 + d1 * d1 + d2 * d2 + d3 * d3;
  for (int off = 32; off; off >>= 1) q += __shfl_xor(q, off, 64);
  if ((tid & 63) == 0) sb2[tid >> 6] = q;
  __syncthreads();
  float var = (sb2[0] + sb2[1] + sb2[2] + sb2[3]) * (1.0f / DIM);
  float rstd = rsqrtf(var + 1e-5f);
  int c = tid * 4;
  float4 gg = *(const float4*)(g + c);
  float4 bb = *(const float4*)(b + c);
  short4v o;
  o.x = f2bf(d0 * rstd * gg.x + bb.x);
  o.y = f2bf(d1 * rstd * gg.y + bb.y);
  o.z = f2bf(d2 * rstd * gg.z + bb.z);
  o.w = f2bf(d3 * rstd * gg.w + bb.w);
  *(short4v*)(out + (size_t)t * DIM + c) = o;
}

// ---------------- GEMM: C[M,N] = A[M,K](bf16) @ B[N,K](bf16)^T ---------------
// TMxTN tile, BK=64, 4 waves as 2x2. XOR chunk swizzle (8 chunks of 16B/row).
// EPI: 0=+bias->bf16(qkv)  1=+bias+resid->f32  4=*wrow->f32  5=silu(a1)*a3->bf16
template <int EPI, bool EXPERT, bool GATHER, bool DUAL, int TM, int TN>
__global__ __launch_bounds__(256, 2) void gemm_k(
    const short* __restrict__ A, const short* __restrict__ B1w,
    const short* __restrict__ B2w, int N, int K,
    const float* __restrict__ bias, const float* __restrict__ resid,
    short* __restrict__ outb, float* __restrict__ outf,
    const int* __restrict__ counts, const int* __restrict__ offsets,
    const int* __restrict__ tok_list, const float* __restrict__ wlist) {
  constexpr int TM2 = TM / 2, TN2 = TN / 2;
  constexpr int MI = TM / 32, NJ = TN / 32;
  constexpr int CA = TM / 32, CB = TN / 32;  // staging chunks/thread (rows*8/256)
  int nt = blockIdx.x, mt = blockIdx.y;
  int e = EXPERT ? blockIdx.z : 0;
  int cnt = 0, aoff = 0;
  if (EXPERT) {
    cnt = counts[e];
    if (mt * TM >= cnt) return;
    aoff = offsets[e];
  }
  const short* Be1 = B1w + (size_t)e * N * K;
  const short* Be3 = DUAL ? (B2w + (size_t)e * N * K) : nullptr;
  int m0 = mt * TM, n0 = nt * TN;
  int tid = threadIdx.x;
  int wave = tid >> 6, lane = tid & 63;
  int quad = lane >> 4, lr = lane & 15;
  int wr = wave >> 1, wc = wave & 1;
  int swz = lr & 7;

  extern __shared__ short smem[];
  short* As = smem;            // TM x 64
  short* Bs1 = smem + TM * 64; // TN x 64
  short* Bs3 = Bs1 + TN * 64;  // TN x 64 (DUAL)

  // staging: LDS slot q=c*256+tid (16B chunks); row=q>>3, kc=q&7; global chunk kc^(row&7)
  const short* Ap[CA];
  const short* Bp[CB];
  const short* Cp[DUAL ? CB : 1];
#pragma unroll
  for (int c = 0; c < CA; c++) {
    int q = c * 256 + tid;
    int row = q >> 3, kc = q & 7;
    int kg = kc ^ (row & 7);
    size_t ar;
    if (GATHER) {
      int i0 = m0 + row; if (i0 > cnt - 1) i0 = cnt - 1;
      ar = (size_t)tok_list[aoff + i0];
    } else if (EXPERT) {
      int i0 = m0 + row; if (i0 > cnt - 1) i0 = cnt - 1;
      ar = (size_t)(aoff + i0);
    } else {
      ar = (size_t)(m0 + row);
    }
    Ap[c] = A + ar * K + kg * 8;
  }
#pragma unroll
  for (int c = 0; c < CB; c++) {
    int q = c * 256 + tid;
    int row = q >> 3, kc = q & 7;
    int kg = kc ^ (row & 7);
    Bp[c] = Be1 + (size_t)(n0 + row) * K + kg * 8;
    if (DUAL) Cp[c] = Be3 + (size_t)(n0 + row) * K + kg * 8;
  }

  f32x4 acc[MI][NJ];
  f32x4 acc3[DUAL ? MI : 1][DUAL ? NJ : 1];
#pragma unroll
  for (int i = 0; i < MI; i++)
#pragma unroll
    for (int j = 0; j < NJ; j++) acc[i][j] = (f32x4){0.f, 0.f, 0.f, 0.f};
  if (DUAL) {
#pragma unroll
    for (int i = 0; i < MI; i++)
#pragma unroll
      for (int j = 0; j < NJ; j++) acc3[i][j] = (f32x4){0.f, 0.f, 0.f, 0.f};
  }

  for (int k0 = 0; k0 < K; k0 += 64) {
#pragma unroll
    for (int c = 0; c < CA; c++)
      async_ld16(Ap[c] + k0, As + (c * 256 + tid) * 8);
#pragma unroll
    for (int c = 0; c < CB; c++)
      async_ld16(Bp[c] + k0, Bs1 + (c * 256 + tid) * 8);
    if (DUAL) {
#pragma unroll
      for (int c = 0; c < CB; c++)
        async_ld16(Cp[c] + k0, Bs3 + (c * 256 + tid) * 8);
    }
    __syncthreads();
    short8 af[2][MI], bf[2][NJ];
#pragma unroll
    for (int kk = 0; kk < 2; kk++)
#pragma unroll
      for (int i = 0; i < MI; i++)
        af[kk][i] = *(const short8*)&As[(wr * TM2 + i * 16 + lr) * 64 +
                                        (((kk * 4 + quad) ^ swz) * 8)];
#pragma unroll
    for (int kk = 0; kk < 2; kk++)
#pragma unroll
      for (int j = 0; j < NJ; j++)
        bf[kk][j] = *(const short8*)&Bs1[(wc * TN2 + j * 16 + lr) * 64 +
                                         (((kk * 4 + quad) ^ swz) * 8)];
#pragma unroll
    for (int kk = 0; kk < 2; kk++)
#pragma unroll
      for (int i = 0; i < MI; i++)
#pragma unroll
        for (int j = 0; j < NJ; j++)
          acc[i][j] = __builtin_amdgcn_mfma_f32_16x16x32_bf16(af[kk][i], bf[kk][j], acc[i][j], 0, 0, 0);
    if (DUAL) {
      short8 cf[2][NJ];
#pragma unroll
      for (int kk = 0; kk < 2; kk++)
#pragma unroll
        for (int j = 0; j < NJ; j++)
          cf[kk][j] = *(const short8*)&Bs3[(wc * TN2 + j * 16 + lr) * 64 +
                                           (((kk * 4 + quad) ^ swz) * 8)];
#pragma unroll
      for (int kk = 0; kk < 2; kk++)
#pragma unroll
        for (int i = 0; i < MI; i++)
#pragma unroll
          for (int j = 0; j < NJ; j++)
            acc3[i][j] = __builtin_amdgcn_mfma_f32_16x16x32_bf16(af[kk][i], cf[kk][j], acc3[i][j], 0, 0, 0);
    }
    __syncthreads();
  }

#pragma unroll
  for (int i = 0; i < MI; i++) {
    int rbase = wr * TM2 + i * 16 + quad * 4;
#pragma unroll
    for (int j = 0; j < NJ; j++) {
      int c = n0 + wc * TN2 + j * 16 + lr;
#pragma unroll
      for (int r = 0; r < 4; r++) {
        int rl = rbase + r;
        float v = acc[i][j][r];
        if (EPI == 0) {
          int t = m0 + rl;
          outb[(size_t)t * N + c] = f2bf(v + bias[c]);
        } else if (EPI == 1) {
          int t = m0 + rl;
          size_t idx = (size_t)t * N + c;
          outf[idx] = v + bias[c] + resid[idx];
        } else if (EPI == 4) {
          int rg = m0 + rl;
          if (rg < cnt) {
            size_t slot = (size_t)(aoff + rg);
            outf[slot * N + c] = v * wlist[slot];
          }
        } else {  // 5: silu(acc)*acc3 -> bf16
          int rg = m0 + rl;
          if (rg < cnt) {
            float v3 = acc3[i][j][r];
            float sv = v / (1.0f + __expf(-v));
            outb[(size_t)(aoff + rg) * N + c] = f2bf(sv * v3);
          }
        }
      }
    }
  }
}

// ---------------- V transpose: qkv V-part -> vt[b][h][dh][seq] ---------------
__global__ __launch_bounds__(256) void vtrans_kernel(const short* __restrict__ qkv,
                                                     short* __restrict__ vt) {
  int st = blockIdx.x;  // seq tile (64)
  int bh = blockIdx.y;
  int b_ = bh >> 4, h = bh & 15;
  int tid = threadIdx.x;
  __shared__ short t[64 * 72];  // [dh][seq], pitch 72
#pragma unroll
  for (int c = 0; c < 2; c++) {
    int q = c * 256 + tid;
    int seq = q >> 3, dhc = q & 7;
    int sk = st * 64 + seq;
    short8 v = *(const short8*)(qkv + (size_t)(sk * NB + b_) * 3072 + 2048 + h * 64 + dhc * 8);
#pragma unroll
    for (int k = 0; k < 8; k++) t[(dhc * 8 + k) * 72 + seq] = v[k];
  }
  __syncthreads();
#pragma unroll
  for (int c = 0; c < 2; c++) {
    int q = c * 256 + tid;
    int dh = q >> 3, sc_ = q & 7;
    short8 o = *(const short8*)&t[dh * 72 + sc_ * 8];
    *(short8*)(vt + ((size_t)bh * 64 + dh) * 2048 + st * 64 + sc_ * 8) = o;
  }
}

// ------- Flash attention: 4 waves x 16 q-rows, K-tile 64, async staging ------
__global__ __launch_bounds__(256) void attn_kernel(const short* __restrict__ qkv,
                                                   const short* __restrict__ vt,
                                                   short* __restrict__ oa) {
  int qt = blockIdx.x;  // 0..31
  int bh = blockIdx.y;  // b*16+h
  int b_ = bh >> 4, h = bh & 15;
  int tid = threadIdx.x, wave = tid >> 6, lane = tid & 63;
  int quad = lane >> 4, lr = lane & 15;
  int swz = lr & 7;

  __shared__ short Ks[64 * 64];
  __shared__ short Vs[64 * 64];
  __shared__ short Ps[4 * 16 * 64];

  int sq = qt * 64 + wave * 16 + lr;
  const short* qrow = qkv + (size_t)(sq * NB + b_) * 3072 + h * 64;
  short8 qa0 = *(const short8*)(qrow + quad * 8);
  short8 qa1 = *(const short8*)(qrow + 32 + quad * 8);

  const short* ksrc[2];
  const short* vsrc[2];
#pragma unroll
  for (int c = 0; c < 2; c++) {
    int q = c * 256 + tid;
    int row = q >> 3, cl = q & 7;
    int cg = cl ^ (row & 7);
    ksrc[c] = qkv + (size_t)(row * NB + b_) * 3072 + 1024 + h * 64 + cg * 8;
    vsrc[c] = vt + ((size_t)bh * 64 + row) * 2048 + cg * 8;
  }

  f32x4 oacc[4];
#pragma unroll
  for (int n = 0; n < 4; n++) oacc[n] = (f32x4){0.f, 0.f, 0.f, 0.f};
  float mrow[4], lsum[4];
#pragma unroll
  for (int r = 0; r < 4; r++) { mrow[r] = -1e30f; lsum[r] = 0.f; }

  const float scale = 0.125f;

  for (int kt = 0; kt < S_LEN / 64; kt++) {
    int seq0 = kt * 64;
#pragma unroll
    for (int c = 0; c < 2; c++) {
      async_ld16(ksrc[c] + (size_t)seq0 * (NB * 3072), Ks + (c * 256 + tid) * 8);
      async_ld16(vsrc[c] + seq0, Vs + (c * 256 + tid) * 8);
    }
    __syncthreads();

    f32x4 sc[4];
#pragma unroll
    for (int g = 0; g < 4; g++) {
      short8 kb0 = *(const short8*)&Ks[(g * 16 + lr) * 64 + (quad ^ swz) * 8];
      short8 kb1 = *(const short8*)&Ks[(g * 16 + lr) * 64 + ((4 + quad) ^ swz) * 8];
      f32x4 z = (f32x4){0.f, 0.f, 0.f, 0.f};
      z = __builtin_amdgcn_mfma_f32_16x16x32_bf16(qa0, kb0, z, 0, 0, 0);
      z = __builtin_amdgcn_mfma_f32_16x16x32_bf16(qa1, kb1, z, 0, 0, 0);
      sc[g] = z;
    }
#pragma unroll
    for (int r = 0; r < 4; r++) {
      float s0 = sc[0][r] * scale, s1 = sc[1][r] * scale;
      float s2 = sc[2][r] * scale, s3 = sc[3][r] * scale;
      float mx = fmaxf(fmaxf(s0, s1), fmaxf(s2, s3));
      mx = fmaxf(mx, __shfl_xor(mx, 1, 64));
      mx = fmaxf(mx, __shfl_xor(mx, 2, 64));
      mx = fmaxf(mx, __shfl_xor(mx, 4, 64));
      mx = fmaxf(mx, __shfl_xor(mx, 8, 64));
      float mnew = fmaxf(mrow[r], mx);
      float alpha = __expf(mrow[r] - mnew);
      float p0 = __expf(s0 - mnew), p1 = __expf(s1 - mnew);
      float p2 = __expf(s2 - mnew), p3 = __expf(s3 - mnew);
      sc[0][r] = p0; sc[1][r] = p1; sc[2][r] = p2; sc[3][r] = p3;
      float ps = (p0 + p1) + (p2 + p3);
      ps += __shfl_xor(ps, 1, 64);
      ps += __shfl_xor(ps, 2, 64);
      ps += __shfl_xor(ps, 4, 64);
      ps += __shfl_xor(ps, 8, 64);
      lsum[r] = lsum[r] * alpha + ps;
      mrow[r] = mnew;
#pragma unroll
      for (int n = 0; n < 4; n++) oacc[n][r] *= alpha;
    }
    short* pw = Ps + wave * 16 * 64;
#pragma unroll
    for (int r = 0; r < 4; r++) {
      int row = quad * 4 + r;
#pragma unroll
      for (int g = 0; g < 4; g++) {
        int cl = (g * 2 + (lr >> 3)) ^ (row & 7);
        pw[row * 64 + cl * 8 + (lr & 7)] = f2bf(sc[g][r]);
      }
    }
    short8 pf0 = *(const short8*)&pw[lr * 64 + (quad ^ swz) * 8];
    short8 pf1 = *(const short8*)&pw[lr * 64 + ((4 + quad) ^ swz) * 8];
#pragma unroll
    for (int n = 0; n < 4; n++) {
      short8 vf0 = *(const short8*)&Vs[(n * 16 + lr) * 64 + (quad ^ swz) * 8];
      short8 vf1 = *(const short8*)&Vs[(n * 16 + lr) * 64 + ((4 + quad) ^ swz) * 8];
      oacc[n] = __builtin_amdgcn_mfma_f32_16x16x32_bf16(pf0, vf0, oacc[n], 0, 0, 0);
      oacc[n] = __builtin_amdgcn_mfma_f32_16x16x32_bf16(pf1, vf1, oacc[n], 0, 0, 0);
    }
    __syncthreads();
  }
#pragma unroll
  for (int r = 0; r < 4; r++) {
    int srow = qt * 64 + wave * 16 + quad * 4 + r;
    short* orow = oa + (size_t)(srow * NB + b_) * 1024 + h * 64;
    float inv = 1.0f / lsum[r];
#pragma unroll
    for (int n = 0; n < 4; n++) orow[n * 16 + lr] = f2bf(oacc[n][r] * inv);
  }
}

// ---------------- Router: full fp32 LN2 + gate logits + top-2 ----------------
__global__ __launch_bounds__(256) void router_kernel(
    const float* __restrict__ xa, const float* __restrict__ g2,
    const float* __restrict__ b2, const float* __restrict__ gate,
    float* __restrict__ logits_out, int* __restrict__ topi,
    float* __restrict__ topw, int* __restrict__ counts) {
  int t = blockIdx.x, tid = threadIdx.x;
  const float* row = xa + (size_t)t * DIM;
  float4 v = *(const float4*)(row + tid * 4);
  __shared__ float sb1[4], sb2[4];
  __shared__ float rede[4][8];
  float s = v.x + v.y + v.z + v.w;
  for (int off = 32; off; off >>= 1) s += __shfl_xor(s, off, 64);
  if ((tid & 63) == 0) sb1[tid >> 6] = s;
  __syncthreads();
  float mean = (sb1[0] + sb1[1] + sb1[2] + sb1[3]) * (1.0f / DIM);
  float d0 = v.x - mean, d1 = v.y - mean, d2 = v.z - mean, d3 = v.w - mean;
  float q = d0 * d0 + d1 * d1 + d2 * d2 + d3 * d3;
  for (int off = 32; off; off >>= 1) q += __shfl_xor(q, off, 64);
  if ((tid & 63) == 0) sb2[tid >> 6] = q;
  __syncthreads();
  float var = (sb2[0] + sb2[1] + sb2[2] + sb2[3]) * (1.0f / DIM);
  float rstd = rsqrtf(var + 1e-5f);
  int c = tid * 4;
  float4 gg = *(const float4*)(g2 + c);
  float4 bb = *(const float4*)(b2 + c);
  float h0 = d0 * rstd * gg.x + bb.x, h1 = d1 * rstd * gg.y + bb.y;
  float h2v = d2 * rstd * gg.z + bb.z, h3 = d3 * rstd * gg.w + bb.w;
  float lg[8];
#pragma unroll
  for (int e = 0; e < 8; e++) {
    float4 gw = *(const float4*)(gate + e * DIM + c);
    lg[e] = h0 * gw.x + h1 * gw.y + h2v * gw.z + h3 * gw.w;
  }
#pragma unroll
  for (int e = 0; e < 8; e++)
    for (int off = 32; off; off >>= 1) lg[e] += __shfl_xor(lg[e], off, 64);
  if ((tid & 63) == 0)
#pragma unroll
    for (int e = 0; e < 8; e++) rede[tid >> 6][e] = lg[e];
  __syncthreads();
  if (tid == 0) {
    float L[8];
#pragma unroll
    for (int e = 0; e < 8; e++)
      L[e] = rede[0][e] + rede[1][e] + rede[2][e] + rede[3][e];
#pragma unroll
    for (int e = 0; e < 8; e++) logits_out[(size_t)t * 8 + e] = L[e];
    int i1 = 0;
    for (int e = 1; e < 8; e++) if (L[e] > L[i1]) i1 = e;
    int i2 = (i1 == 0) ? 1 : 0;
    for (int e = 0; e < 8; e++) if (e != i1 && L[e] > L[i2]) i2 = e;
    float mx = fmaxf(L[i1], L[i2]);
    float p1 = __expf(L[i1] - mx), p2 = __expf(L[i2] - mx);
    float inv = 1.0f / (p1 + p2);
    topi[t * 2] = i1; topi[t * 2 + 1] = i2;
    topw[t * 2] = p1 * inv; topw[t * 2 + 1] = p2 * inv;
    atomicAdd(&counts[i1], 1);
    atomicAdd(&counts[i2], 1);
  }
}

__global__ void scan_kernel(const int* __restrict__ counts, int* __restrict__ offsets,
                            int* __restrict__ cursors) {
  if (threadIdx.x == 0) {
    int acc = 0;
    for (int e = 0; e < 8; e++) {
      offsets[e] = acc;
      cursors[e] = acc;
      acc += counts[e];
    }
  }
}

__global__ __launch_bounds__(256) void scatter_kernel(
    const int* __restrict__ topi, const float* __restrict__ topw,
    int* __restrict__ cursors, int* __restrict__ tok_list,
    float* __restrict__ wlist, int* __restrict__ slot_of) {
  int t = blockIdx.x * 256 + threadIdx.x;
  if (t >= NTOK) return;
#pragma unroll
  for (int k = 0; k < 2; k++) {
    int e = topi[t * 2 + k];
    int pos = atomicAdd(&cursors[e], 1);
    tok_list[pos] = t;
    wlist[pos] = topw[t * 2 + k];
    slot_of[t * 2 + k] = pos;
  }
}

__global__ __launch_bounds__(256) void final_kernel(
    const float* __restrict__ xa, const float* __restrict__ h2,
    const int* __restrict__ slot_of, float* __restrict__ out) {
  size_t i = ((size_t)blockIdx.x * 256 + threadIdx.x) * 4;
  int t = (int)(i >> 10);
  int c = (int)(i & 1023);
  float4 a = *(const float4*)(xa + i);
  int s0 = slot_of[t * 2], s1 = slot_of[t * 2 + 1];
  float4 m0 = *(const float4*)(h2 + (size_t)s0 * 1024 + c);
  float4 m1 = *(const float4*)(h2 + (size_t)s1 * 1024 + c);
  float4 o;
  o.x = a.x + m0.x + m1.x;
  o.y = a.y + m0.y + m1.y;
  o.z = a.z + m0.z + m1.z;
  o.w = a.w + m0.w + m1.w;
  *(float4*)(out + i) = o;
}

extern "C" void kernel_launch(void* const* d_in, const int* in_sizes, int n_in,
                              void* d_out, int out_size, void* d_ws, size_t ws_size,
                              hipStream_t stream) {
  const float* x = (const float*)d_in[0];
  const float* in_w = (const float*)d_in[1];
  const float* in_b = (const float*)d_in[2];
  const float* out_w = (const float*)d_in[3];
  const float* out_b = (const float*)d_in[4];
  const float* ln1g = (const float*)d_in[5];
  const float* ln1b = (const float*)d_in[6];
  const float* ln2g = (const float*)d_in[7];
  const float* ln2b = (const float*)d_in[8];
  const float* gate = (const float*)d_in[9];
  const float* w1 = (const float*)d_in[10];
  const float* w2 = (const float*)d_in[11];
  const float* w3 = (const float*)d_in[12];
  float* out0 = (float*)d_out;
  float* logits = out0 + (size_t)NTOK * DIM;

  char* ws = (char*)d_ws;
  const size_t MB = 1u << 20;
  short* w1b = (short*)(ws);                // [0,64)   dead after w1w3
  short* w3b = (short*)(ws + 64 * MB);      // [64,128) dead after w1w3
  short* w2b = (short*)(ws + 128 * MB);     // [128,192)
  short* in_wb = (short*)(ws + 192 * MB);   // [192,198)
  short* out_wb = (short*)(ws + 198 * MB);  // [198,200)
  short* x_ln1 = (short*)(ws + 200 * MB);   // dead after qkv   } inside s1
  short* qkv = (short*)(ws + 208 * MB);     // dead after attn  } region
  short* o_attn = (short*)(ws + 232 * MB);  // dead after outprj}
  short* vt = (short*)(ws + 240 * MB);      // [240,248) V^T, dead after attn
  short* s1 = (short*)(ws + 200 * MB);      // [200,264) written by w1w3
  float* h2 = (float*)(ws);                 // [0,32) overlays w1b (dead)
  float* x_att = (float*)(ws + 264 * MB);   // [264,280) live to end
  short* x_ln2 = (short*)(ws + 280 * MB);   // [280,288)
  char* ctrl = ws + 288 * MB;
  int* counts = (int*)ctrl;
  int* offsets = counts + 8;
  int* cursors = counts + 16;
  int* topi = (int*)(ctrl + 256);
  float* topw = (float*)(ctrl + 256 + 32 * 1024);
  int* slot_of = (int*)(ctrl + 256 + 64 * 1024);
  int* tok_list = (int*)(ctrl + 256 + 96 * 1024);
  float* wlist = (float*)(ctrl + 256 + 128 * 1024);

  hipMemsetAsync(counts, 0, 32, stream);
  cvt_kernel<<<(NEXP * FFN_DIM * DIM) / 8 / 256, 256, 0, stream>>>(w1, w1b, NEXP * FFN_DIM * DIM);
  cvt_kernel<<<(NEXP * FFN_DIM * DIM) / 8 / 256, 256, 0, stream>>>(w3, w3b, NEXP * FFN_DIM * DIM);
  cvt_kernel<<<(NEXP * FFN_DIM * DIM) / 8 / 256, 256, 0, stream>>>(w2, w2b, NEXP * DIM * FFN_DIM);
  cvt_kernel<<<(3 * DIM * DIM) / 8 / 256, 256, 0, stream>>>(in_w, in_wb, 3 * DIM * DIM);
  cvt_kernel<<<(DIM * DIM) / 8 / 256, 256, 0, stream>>>(out_w, out_wb, DIM * DIM);

  ln_kernel<<<NTOK, 256, 0, stream>>>(x, ln1g, ln1b, x_ln1);
  gemm_k<0, false, false, false, 128, 128><<<dim3(24, 32, 1), 256, 32768, stream>>>(
      x_ln1, in_wb, nullptr, 3072, 1024, in_b, nullptr, qkv, nullptr,
      nullptr, nullptr, nullptr, nullptr);
  vtrans_kernel<<<dim3(32, 32), 256, 0, stream>>>(qkv, vt);
  attn_kernel<<<dim3(32, 32), 256, 0, stream>>>(qkv, vt, o_attn);
  gemm_k<1, false, false, false, 128, 128><<<dim3(8, 32, 1), 256, 32768, stream>>>(
      o_attn, out_wb, nullptr, 1024, 1024, out_b, x, nullptr, x_att,
      nullptr, nullptr, nullptr, nullptr);
  ln_kernel<<<NTOK, 256, 0, stream>>>(x_att, ln2g, ln2b, x_ln2);
  router_kernel<<<NTOK, 256, 0, stream>>>(x_att, ln2g, ln2b, gate, logits, topi, topw, counts);
  scan_kernel<<<1, 64, 0, stream>>>(counts, offsets, cursors);
  scatter_kernel<<<16, 256, 0, stream>>>(topi, topw, cursors, tok_list, wlist, slot_of);
  gemm_k<5, true, true, true, 128, 64><<<dim3(64, 32, 8), 256, 32768, stream>>>(
      x_ln2, w1b, w3b, FFN_DIM, DIM, nullptr, nullptr, s1, nullptr,
      counts, offsets, tok_list, wlist);
  gemm_k<4, true, false, false, 64, 128><<<dim3(8, 64, 8), 256, 24576, stream>>>(
      s1, w2b, nullptr, DIM, FFN_DIM, nullptr, nullptr, nullptr, h2,
      counts, offsets, tok_list, wlist);
  final_kernel<<<4096, 256, 0, stream>>>(x_att, h2, slot_of, out0);
}